// Round 5
// baseline (259.432 us; speedup 1.0000x reference)
//
#include <hip/hip_runtime.h>
#include <math.h>

#define B_    8
#define N_    1025
#define H_    12
#define HD_   64
#define C_    768
#define BH_   (B_*H_)
#define NTOK  (B_*N_)          // 8200
#define SCALE 0.125f
#define NPAD  1092             // bucketT row stride (i-dim, mult of 4)
#define NPADV 1088             // vt row stride (17*64)

#define QKV_ELEMS (BH_*N_*HD_)         // 6,297,600

// ws layout (bytes)
#define XB_OFF_B     ((size_t)0)
#define WQKV_OFF_B   (XB_OFF_B + (size_t)NTOK*C_*2)
#define WPROJ_OFF_B  (WQKV_OFF_B + (size_t)3*C_*C_*2)
#define QB_OFF_B     (WPROJ_OFF_B + (size_t)C_*C_*2)
#define KB_OFF_B     (QB_OFF_B + (size_t)QKV_ELEMS*2)
#define AOB_OFF_B    (KB_OFF_B + (size_t)QKV_ELEMS*2)
#define VT_OFF_B     (AOB_OFF_B + (size_t)QKV_ELEMS*2)
#define BUCKET_OFF_B (VT_OFF_B + (size_t)BH_*HD_*NPADV*2)

typedef __attribute__((ext_vector_type(8))) short s8bf;
typedef __attribute__((ext_vector_type(8))) unsigned short u8s;
typedef __attribute__((ext_vector_type(4))) float v4f;
typedef unsigned short ushort_t;

// async global -> LDS, 16B per lane. LDS dest must be wave-uniform base
// (HW writes base + lane*16); global src is per-lane.
#define GLOAD16(gp, lp) __builtin_amdgcn_global_load_lds( \
    (const __attribute__((address_space(1))) unsigned int*)(gp), \
    (__attribute__((address_space(3))) unsigned int*)(lp), 16, 0, 0)

// raw workgroup barrier with compiler memory fence (no vmcnt drain, unlike __syncthreads)
#define SBAR() do { \
    __builtin_amdgcn_sched_barrier(0); \
    asm volatile("s_barrier" ::: "memory"); \
    __builtin_amdgcn_sched_barrier(0); \
} while (0)

// hand-RNE f32->bf16 (KEEP: v_cvt_pk_bf16_f32 asm path failed absmax in R3 —
// rounding-mode bias accumulated coherently across the bf16 pipeline)
__device__ __forceinline__ unsigned short f2bf(float x) {
    union { float f; unsigned u; } v; v.f = x;
    unsigned r = v.u + 0x7FFFu + ((v.u >> 16) & 1u);
    return (unsigned short)(r >> 16);
}

// ---- bucketT[j][i], integer-exact: bucket = {d2=0:0, d2<=2:1, d2<=12:2, else 3}, cls:7 ----
__global__ void bucket_kernel(unsigned char* __restrict__ bucketT) {
    int tid = blockIdx.x * 256 + threadIdx.x;
    if (tid >= N_ * NPAD) return;
    unsigned ut = (unsigned)tid;
    int j = ut / (unsigned)NPAD, i = ut % (unsigned)NPAD;
    if (i >= N_) i = N_ - 1;
    int bk;
    if (i < 1 || j < 1) {
        bk = 7;
    } else {
        int pi = i - 1, pj = j - 1;
        int dy = (pi >> 5) - (pj >> 5);
        int dx = (pi & 31) - (pj & 31);
        int d2 = dy*dy + dx*dx;
        bk = (d2 == 0) ? 0 : ((d2 <= 2) ? 1 : ((d2 <= 12) ? 2 : 3));
    }
    bucketT[tid] = (unsigned char)bk;
}

// ---------------- fused f32 -> bf16 cast (x, qkv_w, proj_w) ----------------
__global__ __launch_bounds__(256) void cast_kernel(
        const float* __restrict__ x, const float* __restrict__ w1,
        const float* __restrict__ w2,
        ushort_t* __restrict__ xb, ushort_t* __restrict__ w1b,
        ushort_t* __restrict__ w2b) {
    const int NX = NTOK * C_ / 8, NW1 = 3 * C_ * C_ / 8, NW2 = C_ * C_ / 8;
    int g = blockIdx.x * 256 + threadIdx.x;
    const float* src; ushort_t* dst; int idx;
    if (g < NX)                 { src = x;  dst = xb;  idx = g; }
    else if (g < NX + NW1)      { src = w1; dst = w1b; idx = g - NX; }
    else if (g < NX + NW1 + NW2){ src = w2; dst = w2b; idx = g - NX - NW1; }
    else return;
    size_t off = (size_t)idx * 8;
    float4 a = *(const float4*)(src + off);
    float4 c = *(const float4*)(src + off + 4);
    __align__(16) ushort_t h[8] = {f2bf(a.x), f2bf(a.y), f2bf(a.z), f2bf(a.w),
                                   f2bf(c.x), f2bf(c.y), f2bf(c.z), f2bf(c.w)};
    *(u8s*)(dst + off) = *(u8s*)h;
}

// ---------------- bf16 MFMA GEMM: 128x128 tile, BK=64, DOUBLE-BUFFERED global_load_lds ----------------
// T3+T4: 2 LDS buffer pairs; per phase {stage(next) -> s_waitcnt vmcnt(8) -> s_barrier ->
// ds_read+MFMA(cur) -> s_barrier}. vmcnt(8) waits only the PREVIOUS phase's 8 loads (one
// full compute phase to fly); never drains the in-flight prefetch (raw s_barrier, NOT
// __syncthreads which emits vmcnt(0)). Fully unrolled: vmcnt literals + buffer names static.
// LDS content XOR-swizzle (granule ^ row&7): conflict-free frag reads (T2, gated by T3).
__global__ __launch_bounds__(256) void qkv_kernel(
        const ushort_t* __restrict__ xb, const ushort_t* __restrict__ wb,
        ushort_t* __restrict__ qb, ushort_t* __restrict__ kb, ushort_t* __restrict__ vt) {
    __shared__ __align__(16) ushort_t As0[128*64];
    __shared__ __align__(16) ushort_t Bs0[128*64];
    __shared__ __align__(16) ushort_t As1[128*64];
    __shared__ __align__(16) ushort_t Bs1[128*64];
    const int m0 = blockIdx.x * 128, c0 = blockIdx.y * 128;
    const int t = threadIdx.x;
    const int w = t >> 6, lane = t & 63, lc = lane & 15, lq = lane >> 4;
    const int wm = (w >> 1) * 64, wn = (w & 1) * 64;
    const int srow8 = w * 32 + (lane >> 3);                    // + i*8 = row within tile
    const int gsw8  = (((lane & 7) ^ (lane >> 3)) & 7) * 8;    // swizzled source col (ushorts)

    v4f acc[4][4];
#pragma unroll
    for (int mt = 0; mt < 4; mt++)
#pragma unroll
        for (int nt = 0; nt < 4; nt++) acc[mt][nt] = (v4f){0.f, 0.f, 0.f, 0.f};

    auto STAGE = [&](ushort_t* Ad, ushort_t* Bd, int k0) {
#pragma unroll
        for (int i = 0; i < 4; i++) {
            int row = srow8 + i * 8;
            int m = m0 + row; if (m > NTOK - 1) m = NTOK - 1;   // clamp: dup reads, rows masked in epilogue
            GLOAD16(xb + (size_t)m * C_ + k0 + gsw8,           &Ad[(w*32 + i*8) * 64]);
            GLOAD16(wb + (size_t)(c0 + row) * C_ + k0 + gsw8,  &Bd[(w*32 + i*8) * 64]);
        }
    };
    auto COMPUTE = [&](const ushort_t* A, const ushort_t* B) {
#pragma unroll
        for (int kk = 0; kk < 64; kk += 32) {
            s8bf af[4], bf[4];
#pragma unroll
            for (int mt = 0; mt < 4; mt++)
                af[mt] = *(const s8bf*)&A[(wm + mt*16 + lc) * 64 + ((((kk>>3) + lq) ^ (lc & 7)) * 8)];
#pragma unroll
            for (int nt = 0; nt < 4; nt++)
                bf[nt] = *(const s8bf*)&B[(wn + nt*16 + lc) * 64 + ((((kk>>3) + lq) ^ (lc & 7)) * 8)];
#pragma unroll
            for (int mt = 0; mt < 4; mt++)
#pragma unroll
                for (int nt = 0; nt < 4; nt++)
                    acc[mt][nt] = __builtin_amdgcn_mfma_f32_16x16x32_bf16(af[mt], bf[nt], acc[mt][nt], 0, 0, 0);
        }
    };

    STAGE(As0, Bs0, 0);
#pragma unroll
    for (int it = 0; it < 6; ++it) {
        const int k0 = it * 128;
        // ---- phase A: compute buf0 @ k0, prefetch buf1 @ k0+64 ----
        if (k0 + 64 < C_) {
            STAGE(As1, Bs1, k0 + 64);
            asm volatile("s_waitcnt vmcnt(8)" ::: "memory");   // buf0's 8 loads landed
        } else {
            asm volatile("s_waitcnt vmcnt(0)" ::: "memory");
        }
        SBAR();                                                // all waves' buf0 ready
        COMPUTE(As0, Bs0);
        SBAR();                                                // buf0 reads done before restage
        // ---- phase B: compute buf1 @ k0+64, prefetch buf0 @ k0+128 ----
        if (k0 + 128 < C_) {
            STAGE(As0, Bs0, k0 + 128);
            asm volatile("s_waitcnt vmcnt(8)" ::: "memory");   // buf1's 8 loads landed
        } else {
            asm volatile("s_waitcnt vmcnt(0)" ::: "memory");
        }
        SBAR();
        COMPUTE(As1, Bs1);
        if (it < 5) SBAR();                                    // buf1 reads done before next restage
    }

#pragma unroll
    for (int mt = 0; mt < 4; mt++) {
#pragma unroll
        for (int r = 0; r < 4; r++) {
            int m = m0 + wm + mt*16 + lq*4 + r;
            if (m >= NTOK) continue;
            unsigned um = (unsigned)m;
            int b = um / (unsigned)N_, n = um % (unsigned)N_;
#pragma unroll
            for (int nt = 0; nt < 4; nt++) {
                int c = c0 + wn + nt*16 + lc;
                int comp = c / C_, rem = c % C_;
                int h = rem >> 6, d0 = rem & 63;
                float val = acc[mt][nt][r] * ((comp == 0) ? SCALE : 1.0f);
                if (comp == 2) {
                    vt[((size_t)((b*H_ + h)*HD_ + d0))*NPADV + n] = f2bf(val);
                } else {
                    ushort_t* dst = (comp == 0) ? qb : kb;
                    dst[((size_t)((b*H_ + h)*N_ + n))*HD_ + d0] = f2bf(val);
                }
            }
        }
    }
}

// ---------------- attention: r4 structure + XCD affinity + no-max + prefetch ----------------
// Qs aliased onto Vs (Q frags are register-resident before the jt loop's first barrier).
#define LDT  72
#define LUTS 9

__global__ __launch_bounds__(256) void attn_kernel(
        const ushort_t* __restrict__ qb, const ushort_t* __restrict__ kb,
        const ushort_t* __restrict__ vt, const float* __restrict__ rpe,
        const unsigned char* __restrict__ bucketT, ushort_t* __restrict__ ao) {
    __shared__ __align__(16) ushort_t Ks[64*LDT];
    __shared__ __align__(16) ushort_t Vs[64*LDT];   // prologue alias: Q tile; loop: V^T Vs[d][j]
    __shared__ __align__(16) ushort_t Ps[64*LDT];   // prologue alias rows 0..15: rpe^T
    __shared__ float lut[64*LUTS];

    const int bh = blockIdx.x, it = blockIdx.y;     // bh-major: all i-tiles of bh on one XCD
    const int b  = bh / H_, hh = bh % H_;
    const int i0 = it * 64;
    const int t  = threadIdx.x;
    const int w  = t >> 6, lane = t & 63, lc = lane & 15, lq = lane >> 4;
    const int row_w = w * 16;                       // wave strip (16 rows)

    const ushort_t* qp = qb + (size_t)bh * N_ * HD_;
    const ushort_t* kp = kb + (size_t)bh * N_ * HD_;
    const ushort_t* vp = vt + (size_t)bh * HD_ * NPADV;

    // ---- stage Q into Vs (zero rows >= N) ----
    {
        int row = t >> 2, d0 = (t & 3) * 16;
        int gi = i0 + row;
        u8s h0 = (u8s)0, h1 = (u8s)0;
        if (gi < N_) {
            h0 = *(const u8s*)(qp + (size_t)gi * HD_ + d0);
            h1 = *(const u8s*)(qp + (size_t)gi * HD_ + d0 + 8);
        }
        *(u8s*)&Vs[row*LDT + d0]     = h0;
        *(u8s*)&Vs[row*LDT + d0 + 8] = h1;
    }
    // ---- stage rpe^T into Ps rows 0..7 (row=m, col=d), zero rows 8..15 ----
    if (t < 64) {
        float4 r0 = *(const float4*)(rpe + t*8);
        float4 r1 = *(const float4*)(rpe + t*8 + 4);
        Ps[0*LDT + t] = f2bf(r0.x); Ps[1*LDT + t] = f2bf(r0.y);
        Ps[2*LDT + t] = f2bf(r0.z); Ps[3*LDT + t] = f2bf(r0.w);
        Ps[4*LDT + t] = f2bf(r1.x); Ps[5*LDT + t] = f2bf(r1.y);
        Ps[6*LDT + t] = f2bf(r1.z); Ps[7*LDT + t] = f2bf(r1.w);
    } else if (t < 128) {
        int idx = t - 64;
        int m = 8 + (idx >> 3), c = (idx & 7) * 8;
        *(u8s*)&Ps[m*LDT + c] = (u8s)0;
    }
    __syncthreads();

    // ---- Q A-fragments (held all K-tiles) ----
    s8bf qf0 = *(s8bf*)&Vs[(row_w + lc)*LDT + lq*8];
    s8bf qf1 = *(s8bf*)&Vs[(row_w + lc)*LDT + 32 + lq*8];

    // ---- lut = Q @ rpe via MFMA (wave-private rows; same-wave DS ordering) ----
    {
        s8bf rf0 = *(s8bf*)&Ps[lc*LDT + lq*8];
        s8bf rf1 = *(s8bf*)&Ps[lc*LDT + 32 + lq*8];
        v4f la = (v4f){0.f, 0.f, 0.f, 0.f};
        la = __builtin_amdgcn_mfma_f32_16x16x32_bf16(qf0, rf0, la, 0, 0, 0);
        la = __builtin_amdgcn_mfma_f32_16x16x32_bf16(qf1, rf1, la, 0, 0, 0);
        if (lc < 8) {
#pragma unroll
            for (int r = 0; r < 4; r++)
                lut[(row_w + lq*4 + r)*LUTS + lc] = la[r];
        }
    }

    // ---- prologue prefetch: K/V tile 0 + bucket tile 0 ----
    const int srow = t >> 2, sd0 = (t & 3) * 16;
    u8s krg0, krg1, vrg0, vrg1;
    {
        const ushort_t* ks = kp + (size_t)srow * HD_ + sd0;
        krg0 = *(const u8s*)ks; krg1 = *(const u8s*)(ks + 8);
        const ushort_t* vs = vp + (size_t)srow * NPADV + sd0;
        vrg0 = *(const u8s*)vs; vrg1 = *(const u8s*)(vs + 8);
    }
    const int ibase = i0 + row_w + lq*4;   // 4 consecutive i's per lane (<= 1084, fits NPAD)
    unsigned bk4[4];
#pragma unroll
    for (int t4 = 0; t4 < 4; t4++) {
        int jb = t4*16 + lc;
        bk4[t4] = *(const unsigned*)(bucketT + (size_t)jb * NPAD + ibase);
    }

    v4f o[4];
    float lsum[4];
#pragma unroll
    for (int dt = 0; dt < 4; dt++) o[dt] = (v4f){0.f, 0.f, 0.f, 0.f};
#pragma unroll
    for (int r = 0; r < 4; r++) lsum[r] = 0.f;

    for (int jt = 0; jt < 17; jt++) {
        const int j0 = jt * 64;
        __syncthreads();   // prev tile's frag reads (and prologue qf) done
        {
            ushort_t* kd = &Ks[srow*LDT + sd0];
            *(u8s*)kd = krg0; *(u8s*)(kd + 8) = krg1;
            ushort_t* vd = &Vs[srow*LDT + sd0];
            *(u8s*)vd = vrg0; *(u8s*)(vd + 8) = vrg1;
        }
        __syncthreads();   // staging visible

        // prefetch next tile's K/V + buckets (hidden behind this tile's compute)
        unsigned bk4n[4];
        if (jt < 16) {
            int gj = j0 + 64 + srow; if (gj > N_ - 1) gj = N_ - 1;
            const ushort_t* ks = kp + (size_t)gj * HD_ + sd0;
            krg0 = *(const u8s*)ks; krg1 = *(const u8s*)(ks + 8);
            const ushort_t* vs = vp + (size_t)srow * NPADV + (j0 + 64) + sd0;
            vrg0 = *(const u8s*)vs; vrg1 = *(const u8s*)(vs + 8);
#pragma unroll
            for (int t4 = 0; t4 < 4; t4++) {
                int jb = j0 + 64 + t4*16 + lc; if (jb > N_ - 1) jb = N_ - 1;
                bk4n[t4] = *(const unsigned*)(bucketT + (size_t)jb * NPAD + ibase);
            }
        }

        // ---- S = Q K^T (4 col tiles) ----
        v4f acc[4];
#pragma unroll
        for (int t4 = 0; t4 < 4; t4++) acc[t4] = (v4f){0.f, 0.f, 0.f, 0.f};
#pragma unroll
        for (int t4 = 0; t4 < 4; t4++) {
            s8bf kf0 = *(s8bf*)&Ks[(t4*16 + lc)*LDT + lq*8];
            s8bf kf1 = *(s8bf*)&Ks[(t4*16 + lc)*LDT + 32 + lq*8];
            acc[t4] = __builtin_amdgcn_mfma_f32_16x16x32_bf16(qf0, kf0, acc[t4], 0, 0, 0);
            acc[t4] = __builtin_amdgcn_mfma_f32_16x16x32_bf16(qf1, kf1, acc[t4], 0, 0, 0);
        }

        // ---- bias + exp (no max; logits provably small) + P write (wave-private) ----
        // per-el j<N mask only matters for jt==16 (j>=1024): hoisted to uniform branch
#pragma unroll
        for (int t4 = 0; t4 < 4; t4++) {
#pragma unroll
            for (int r = 0; r < 4; r++) {
                int bk = (bk4[t4] >> (8*r)) & 0xFF;
                float sv = acc[t4][r] + lut[(row_w + lq*4 + r)*LUTS + bk];
                float p = __expf(sv);
                if (jt == 16 && (t4*16 + lc) > 0) p = 0.f;
                lsum[r] += p;
                Ps[(row_w + lq*4 + r)*LDT + t4*16 + lc] = f2bf(p);
            }
        }
#pragma unroll
        for (int t4 = 0; t4 < 4; t4++) bk4[t4] = bk4n[t4];

        // ---- O += P V (same-wave DS ordering) ----
        s8bf pf0 = *(s8bf*)&Ps[(row_w + lc)*LDT + lq*8];
        s8bf pf1 = *(s8bf*)&Ps[(row_w + lc)*LDT + 32 + lq*8];
#pragma unroll
        for (int dt = 0; dt < 4; dt++) {
            s8bf vf0 = *(s8bf*)&Vs[(dt*16 + lc)*LDT + lq*8];
            s8bf vf1 = *(s8bf*)&Vs[(dt*16 + lc)*LDT + 32 + lq*8];
            o[dt] = __builtin_amdgcn_mfma_f32_16x16x32_bf16(pf0, vf0, o[dt], 0, 0, 0);
            o[dt] = __builtin_amdgcn_mfma_f32_16x16x32_bf16(pf1, vf1, o[dt], 0, 0, 0);
        }
    }

    // ---- epilogue: reduce lsum over 16 col-lanes, normalize, store bf16 ----
#pragma unroll
    for (int r = 0; r < 4; r++) {
        float sm = lsum[r];
        sm += __shfl_xor(sm, 1);
        sm += __shfl_xor(sm, 2);
        sm += __shfl_xor(sm, 4);
        sm += __shfl_xor(sm, 8);
        int i = i0 + row_w + lq*4 + r;
        if (i < N_) {
            float inv = 1.0f / sm;
#pragma unroll
            for (int dt = 0; dt < 4; dt++)
                ao[((size_t)(b*N_ + i))*C_ + hh*HD_ + dt*16 + lc] = f2bf(o[dt][r] * inv);
        }
    }
}

// ---------------- proj: out(8200x768) = aob @ wprojb^T + bias, f32 out ----------------
// same T3+T4 double-buffered pipeline as qkv_kernel
__global__ __launch_bounds__(256) void proj_kernel(
        const ushort_t* __restrict__ ab, const ushort_t* __restrict__ wb,
        const float* __restrict__ bias, float* __restrict__ out) {
    __shared__ __align__(16) ushort_t As0[128*64];
    __shared__ __align__(16) ushort_t Bs0[128*64];
    __shared__ __align__(16) ushort_t As1[128*64];
    __shared__ __align__(16) ushort_t Bs1[128*64];
    const int m0 = blockIdx.x * 128, c0 = blockIdx.y * 128;
    const int t = threadIdx.x;
    const int w = t >> 6, lane = t & 63, lc = lane & 15, lq = lane >> 4;
    const int wm = (w >> 1) * 64, wn = (w & 1) * 64;
    const int srow8 = w * 32 + (lane >> 3);
    const int gsw8  = (((lane & 7) ^ (lane >> 3)) & 7) * 8;

    v4f acc[4][4];
#pragma unroll
    for (int mt = 0; mt < 4; mt++)
#pragma unroll
        for (int nt = 0; nt < 4; nt++) acc[mt][nt] = (v4f){0.f, 0.f, 0.f, 0.f};

    auto STAGE = [&](ushort_t* Ad, ushort_t* Bd, int k0) {
#pragma unroll
        for (int i = 0; i < 4; i++) {
            int row = srow8 + i * 8;
            int m = m0 + row; if (m > NTOK - 1) m = NTOK - 1;
            GLOAD16(ab + (size_t)m * C_ + k0 + gsw8,           &Ad[(w*32 + i*8) * 64]);
            GLOAD16(wb + (size_t)(c0 + row) * C_ + k0 + gsw8,  &Bd[(w*32 + i*8) * 64]);
        }
    };
    auto COMPUTE = [&](const ushort_t* A, const ushort_t* B) {
#pragma unroll
        for (int kk = 0; kk < 64; kk += 32) {
            s8bf af[4], bf[4];
#pragma unroll
            for (int mt = 0; mt < 4; mt++)
                af[mt] = *(const s8bf*)&A[(wm + mt*16 + lc) * 64 + ((((kk>>3) + lq) ^ (lc & 7)) * 8)];
#pragma unroll
            for (int nt = 0; nt < 4; nt++)
                bf[nt] = *(const s8bf*)&B[(wn + nt*16 + lc) * 64 + ((((kk>>3) + lq) ^ (lc & 7)) * 8)];
#pragma unroll
            for (int mt = 0; mt < 4; mt++)
#pragma unroll
                for (int nt = 0; nt < 4; nt++)
                    acc[mt][nt] = __builtin_amdgcn_mfma_f32_16x16x32_bf16(af[mt], bf[nt], acc[mt][nt], 0, 0, 0);
        }
    };

    STAGE(As0, Bs0, 0);
#pragma unroll
    for (int it = 0; it < 6; ++it) {
        const int k0 = it * 128;
        if (k0 + 64 < C_) {
            STAGE(As1, Bs1, k0 + 64);
            asm volatile("s_waitcnt vmcnt(8)" ::: "memory");
        } else {
            asm volatile("s_waitcnt vmcnt(0)" ::: "memory");
        }
        SBAR();
        COMPUTE(As0, Bs0);
        SBAR();
        if (k0 + 128 < C_) {
            STAGE(As0, Bs0, k0 + 128);
            asm volatile("s_waitcnt vmcnt(8)" ::: "memory");
        } else {
            asm volatile("s_waitcnt vmcnt(0)" ::: "memory");
        }
        SBAR();
        COMPUTE(As1, Bs1);
        if (it < 5) SBAR();
    }

    float pb[4];
#pragma unroll
    for (int nt = 0; nt < 4; nt++) pb[nt] = bias[c0 + wn + nt*16 + lc];
#pragma unroll
    for (int mt = 0; mt < 4; mt++) {
#pragma unroll
        for (int r = 0; r < 4; r++) {
            int m = m0 + wm + mt*16 + lq*4 + r;
            if (m >= NTOK) continue;
#pragma unroll
            for (int nt = 0; nt < 4; nt++) {
                int c = c0 + wn + nt*16 + lc;
                out[(size_t)m * C_ + c] = acc[mt][nt][r] + pb[nt];
            }
        }
    }
}

extern "C" void kernel_launch(void* const* d_in, const int* in_sizes, int n_in,
                              void* d_out, int out_size, void* d_ws, size_t ws_size,
                              hipStream_t stream) {
    const float* x      = (const float*)d_in[0];
    const float* qkv_w  = (const float*)d_in[1];
    const float* proj_w = (const float*)d_in[2];
    const float* proj_b = (const float*)d_in[3];
    const float* rpe_w  = (const float*)d_in[4];
    float* out = (float*)d_out;

    char* ws = (char*)d_ws;
    ushort_t* xb   = (ushort_t*)(ws + XB_OFF_B);
    ushort_t* wqkv = (ushort_t*)(ws + WQKV_OFF_B);
    ushort_t* wprj = (ushort_t*)(ws + WPROJ_OFF_B);
    ushort_t* qb   = (ushort_t*)(ws + QB_OFF_B);
    ushort_t* kb   = (ushort_t*)(ws + KB_OFF_B);
    ushort_t* aob  = (ushort_t*)(ws + AOB_OFF_B);
    ushort_t* vt   = (ushort_t*)(ws + VT_OFF_B);
    unsigned char* bucketT = (unsigned char*)(ws + BUCKET_OFF_B);

    const int ncast = (NTOK*C_ + 3*C_*C_ + C_*C_) / 8;
    bucket_kernel<<<dim3((N_*NPAD + 255)/256), 256, 0, stream>>>(bucketT);
    cast_kernel<<<dim3((ncast + 255)/256), 256, 0, stream>>>(x, qkv_w, proj_w, xb, wqkv, wprj);
    qkv_kernel<<<dim3(65, 18), 256, 0, stream>>>(xb, wqkv, qb, kb, vt);
    attn_kernel<<<dim3(96, 17), 256, 0, stream>>>(qb, kb, vt, rpe_w, bucketT, aob);
    proj_kernel<<<dim3(65, 6), 256, 0, stream>>>(aob, wprj, proj_b, out);
}

// Round 6
// 251.680 us; speedup vs baseline: 1.0308x; 1.0308x over previous
//
#include <hip/hip_runtime.h>
#include <math.h>

#define B_    8
#define N_    1025
#define H_    12
#define HD_   64
#define C_    768
#define BH_   (B_*H_)
#define NTOK  (B_*N_)          // 8200
#define SCALE 0.125f
#define NPAD  1092             // bucketT row stride (mult of 4); table is SYMMETRIC: [a][b]=bucket(a,b)
#define NPADV 1088             // vt row stride (17*64)

#define QKV_ELEMS (BH_*N_*HD_)         // 6,297,600

// ws layout (bytes)
#define XB_OFF_B     ((size_t)0)
#define WQKV_OFF_B   (XB_OFF_B + (size_t)NTOK*C_*2)
#define WPROJ_OFF_B  (WQKV_OFF_B + (size_t)3*C_*C_*2)
#define QB_OFF_B     (WPROJ_OFF_B + (size_t)C_*C_*2)
#define KB_OFF_B     (QB_OFF_B + (size_t)QKV_ELEMS*2)
#define AOB_OFF_B    (KB_OFF_B + (size_t)QKV_ELEMS*2)
#define VT_OFF_B     (AOB_OFF_B + (size_t)QKV_ELEMS*2)
#define BUCKET_OFF_B (VT_OFF_B + (size_t)BH_*HD_*NPADV*2)

typedef __attribute__((ext_vector_type(8))) short s8bf;
typedef __attribute__((ext_vector_type(8))) unsigned short u8s;
typedef __attribute__((ext_vector_type(4))) float v4f;
typedef unsigned short ushort_t;

// async global -> LDS, 16B per lane. LDS dest must be wave-uniform base
// (HW writes base + lane*16); global src is per-lane.
#define GLOAD16(gp, lp) __builtin_amdgcn_global_load_lds( \
    (const __attribute__((address_space(1))) unsigned int*)(gp), \
    (__attribute__((address_space(3))) unsigned int*)(lp), 16, 0, 0)

// raw workgroup barrier with compiler memory fence (no vmcnt drain, unlike __syncthreads)
#define SBAR() do { \
    __builtin_amdgcn_sched_barrier(0); \
    asm volatile("s_barrier" ::: "memory"); \
    __builtin_amdgcn_sched_barrier(0); \
} while (0)

// hand-RNE f32->bf16 (KEEP: v_cvt_pk_bf16_f32 asm path failed absmax in R3 —
// rounding-mode bias accumulated coherently across the bf16 pipeline)
__device__ __forceinline__ unsigned short f2bf(float x) {
    union { float f; unsigned u; } v; v.f = x;
    unsigned r = v.u + 0x7FFFu + ((v.u >> 16) & 1u);
    return (unsigned short)(r >> 16);
}

// ---- bucketT[a][b] = bucket(a,b), integer-exact & SYMMETRIC: {d2=0:0, d2<=2:1, d2<=12:2, else 3}, cls:7 ----
__global__ void bucket_kernel(unsigned char* __restrict__ bucketT) {
    int tid = blockIdx.x * 256 + threadIdx.x;
    if (tid >= N_ * NPAD) return;
    unsigned ut = (unsigned)tid;
    int j = ut / (unsigned)NPAD, i = ut % (unsigned)NPAD;
    if (i >= N_) i = N_ - 1;
    int bk;
    if (i < 1 || j < 1) {
        bk = 7;
    } else {
        int pi = i - 1, pj = j - 1;
        int dy = (pi >> 5) - (pj >> 5);
        int dx = (pi & 31) - (pj & 31);
        int d2 = dy*dy + dx*dx;
        bk = (d2 == 0) ? 0 : ((d2 <= 2) ? 1 : ((d2 <= 12) ? 2 : 3));
    }
    bucketT[tid] = (unsigned char)bk;
}

// ---------------- fused f32 -> bf16 cast (x, qkv_w, proj_w) ----------------
__global__ __launch_bounds__(256) void cast_kernel(
        const float* __restrict__ x, const float* __restrict__ w1,
        const float* __restrict__ w2,
        ushort_t* __restrict__ xb, ushort_t* __restrict__ w1b,
        ushort_t* __restrict__ w2b) {
    const int NX = NTOK * C_ / 8, NW1 = 3 * C_ * C_ / 8, NW2 = C_ * C_ / 8;
    int g = blockIdx.x * 256 + threadIdx.x;
    const float* src; ushort_t* dst; int idx;
    if (g < NX)                 { src = x;  dst = xb;  idx = g; }
    else if (g < NX + NW1)      { src = w1; dst = w1b; idx = g - NX; }
    else if (g < NX + NW1 + NW2){ src = w2; dst = w2b; idx = g - NX - NW1; }
    else return;
    size_t off = (size_t)idx * 8;
    float4 a = *(const float4*)(src + off);
    float4 c = *(const float4*)(src + off + 4);
    __align__(16) ushort_t h[8] = {f2bf(a.x), f2bf(a.y), f2bf(a.z), f2bf(a.w),
                                   f2bf(c.x), f2bf(c.y), f2bf(c.z), f2bf(c.w)};
    *(u8s*)(dst + off) = *(u8s*)h;
}

// ---------------- bf16 MFMA GEMM: 128x128 tile, BK=64, DOUBLE-BUFFERED global_load_lds ----------------
__global__ __launch_bounds__(256) void qkv_kernel(
        const ushort_t* __restrict__ xb, const ushort_t* __restrict__ wb,
        ushort_t* __restrict__ qb, ushort_t* __restrict__ kb, ushort_t* __restrict__ vt) {
    __shared__ __align__(16) ushort_t As0[128*64];
    __shared__ __align__(16) ushort_t Bs0[128*64];
    __shared__ __align__(16) ushort_t As1[128*64];
    __shared__ __align__(16) ushort_t Bs1[128*64];
    const int m0 = blockIdx.x * 128, c0 = blockIdx.y * 128;
    const int t = threadIdx.x;
    const int w = t >> 6, lane = t & 63, lc = lane & 15, lq = lane >> 4;
    const int wm = (w >> 1) * 64, wn = (w & 1) * 64;
    const int srow8 = w * 32 + (lane >> 3);                    // + i*8 = row within tile
    const int gsw8  = (((lane & 7) ^ (lane >> 3)) & 7) * 8;    // swizzled source col (ushorts)

    v4f acc[4][4];
#pragma unroll
    for (int mt = 0; mt < 4; mt++)
#pragma unroll
        for (int nt = 0; nt < 4; nt++) acc[mt][nt] = (v4f){0.f, 0.f, 0.f, 0.f};

    auto STAGE = [&](ushort_t* Ad, ushort_t* Bd, int k0) {
#pragma unroll
        for (int i = 0; i < 4; i++) {
            int row = srow8 + i * 8;
            int m = m0 + row; if (m > NTOK - 1) m = NTOK - 1;   // clamp: dup reads, rows masked in epilogue
            GLOAD16(xb + (size_t)m * C_ + k0 + gsw8,           &Ad[(w*32 + i*8) * 64]);
            GLOAD16(wb + (size_t)(c0 + row) * C_ + k0 + gsw8,  &Bd[(w*32 + i*8) * 64]);
        }
    };
    auto COMPUTE = [&](const ushort_t* A, const ushort_t* B) {
#pragma unroll
        for (int kk = 0; kk < 64; kk += 32) {
            s8bf af[4], bf[4];
#pragma unroll
            for (int mt = 0; mt < 4; mt++)
                af[mt] = *(const s8bf*)&A[(wm + mt*16 + lc) * 64 + ((((kk>>3) + lq) ^ (lc & 7)) * 8)];
#pragma unroll
            for (int nt = 0; nt < 4; nt++)
                bf[nt] = *(const s8bf*)&B[(wn + nt*16 + lc) * 64 + ((((kk>>3) + lq) ^ (lc & 7)) * 8)];
#pragma unroll
            for (int mt = 0; mt < 4; mt++)
#pragma unroll
                for (int nt = 0; nt < 4; nt++)
                    acc[mt][nt] = __builtin_amdgcn_mfma_f32_16x16x32_bf16(af[mt], bf[nt], acc[mt][nt], 0, 0, 0);
        }
    };

    STAGE(As0, Bs0, 0);
#pragma unroll
    for (int it = 0; it < 6; ++it) {
        const int k0 = it * 128;
        if (k0 + 64 < C_) {
            STAGE(As1, Bs1, k0 + 64);
            asm volatile("s_waitcnt vmcnt(8)" ::: "memory");
        } else {
            asm volatile("s_waitcnt vmcnt(0)" ::: "memory");
        }
        SBAR();
        COMPUTE(As0, Bs0);
        SBAR();
        if (k0 + 128 < C_) {
            STAGE(As0, Bs0, k0 + 128);
            asm volatile("s_waitcnt vmcnt(8)" ::: "memory");
        } else {
            asm volatile("s_waitcnt vmcnt(0)" ::: "memory");
        }
        SBAR();
        COMPUTE(As1, Bs1);
        if (it < 5) SBAR();
    }

#pragma unroll
    for (int mt = 0; mt < 4; mt++) {
#pragma unroll
        for (int r = 0; r < 4; r++) {
            int m = m0 + wm + mt*16 + lq*4 + r;
            if (m >= NTOK) continue;
            unsigned um = (unsigned)m;
            int b = um / (unsigned)N_, n = um % (unsigned)N_;
#pragma unroll
            for (int nt = 0; nt < 4; nt++) {
                int c = c0 + wn + nt*16 + lc;
                int comp = c / C_, rem = c % C_;
                int h = rem >> 6, d0 = rem & 63;
                float val = acc[mt][nt][r] * ((comp == 0) ? SCALE : 1.0f);
                if (comp == 2) {
                    vt[((size_t)((b*H_ + h)*HD_ + d0))*NPADV + n] = f2bf(val);
                } else {
                    ushort_t* dst = (comp == 0) ? qb : kb;
                    dst[((size_t)((b*H_ + h)*N_ + n))*HD_ + d0] = f2bf(val);
                }
            }
        }
    }
}

// ---------------- attention: SWAPPED QK^T (T12) — lane owns one Q-row ----------------
// mfma(K,Q) = S^T: D col=lc -> i (Q-row), rows lq*4+r -> j. Per lane: fixed i, 16 j's.
// P written as 4x ds_write_b64 (j-consecutive) instead of 16x ds_write_b16.
// PV fragment reads (P as A-frag, lane=row i) and O layout UNCHANGED.
// lsum: per-lane scalar; reduced over lq-lanes + redistributed via lut col 8.
#define LDT  72
#define LUTS 9

__global__ __launch_bounds__(256) void attn_kernel(
        const ushort_t* __restrict__ qb, const ushort_t* __restrict__ kb,
        const ushort_t* __restrict__ vt, const float* __restrict__ rpe,
        const unsigned char* __restrict__ bucketT, ushort_t* __restrict__ ao) {
    __shared__ __align__(16) ushort_t Ks[64*LDT];
    __shared__ __align__(16) ushort_t Vs[64*LDT];   // prologue alias: Q tile; loop: V^T Vs[d][j]
    __shared__ __align__(16) ushort_t Ps[64*LDT];   // prologue alias rows 0..15: rpe^T
    __shared__ float lut[64*LUTS];                  // col 8: lsum broadcast (epilogue)

    const int bh = blockIdx.x, it = blockIdx.y;     // bh-major: all i-tiles of bh on one XCD
    const int b  = bh / H_, hh = bh % H_;
    const int i0 = it * 64;
    const int t  = threadIdx.x;
    const int w  = t >> 6, lane = t & 63, lc = lane & 15, lq = lane >> 4;
    const int row_w = w * 16;                       // wave strip (16 rows)

    const ushort_t* qp = qb + (size_t)bh * N_ * HD_;
    const ushort_t* kp = kb + (size_t)bh * N_ * HD_;
    const ushort_t* vp = vt + (size_t)bh * HD_ * NPADV;

    // ---- stage Q into Vs (zero rows >= N) ----
    {
        int row = t >> 2, d0 = (t & 3) * 16;
        int gi = i0 + row;
        u8s h0 = (u8s)0, h1 = (u8s)0;
        if (gi < N_) {
            h0 = *(const u8s*)(qp + (size_t)gi * HD_ + d0);
            h1 = *(const u8s*)(qp + (size_t)gi * HD_ + d0 + 8);
        }
        *(u8s*)&Vs[row*LDT + d0]     = h0;
        *(u8s*)&Vs[row*LDT + d0 + 8] = h1;
    }
    // ---- stage rpe^T into Ps rows 0..7 (row=m, col=d), zero rows 8..15 ----
    if (t < 64) {
        float4 r0 = *(const float4*)(rpe + t*8);
        float4 r1 = *(const float4*)(rpe + t*8 + 4);
        Ps[0*LDT + t] = f2bf(r0.x); Ps[1*LDT + t] = f2bf(r0.y);
        Ps[2*LDT + t] = f2bf(r0.z); Ps[3*LDT + t] = f2bf(r0.w);
        Ps[4*LDT + t] = f2bf(r1.x); Ps[5*LDT + t] = f2bf(r1.y);
        Ps[6*LDT + t] = f2bf(r1.z); Ps[7*LDT + t] = f2bf(r1.w);
    } else if (t < 128) {
        int idx = t - 64;
        int m = 8 + (idx >> 3), c = (idx & 7) * 8;
        *(u8s*)&Ps[m*LDT + c] = (u8s)0;
    }
    __syncthreads();

    // ---- Q A-fragments (held all K-tiles) ----
    s8bf qf0 = *(s8bf*)&Vs[(row_w + lc)*LDT + lq*8];
    s8bf qf1 = *(s8bf*)&Vs[(row_w + lc)*LDT + 32 + lq*8];

    // ---- lut = Q @ rpe via MFMA (wave-private rows; consumed before first P overwrite) ----
    {
        s8bf rf0 = *(s8bf*)&Ps[lc*LDT + lq*8];
        s8bf rf1 = *(s8bf*)&Ps[lc*LDT + 32 + lq*8];
        v4f la = (v4f){0.f, 0.f, 0.f, 0.f};
        la = __builtin_amdgcn_mfma_f32_16x16x32_bf16(qf0, rf0, la, 0, 0, 0);
        la = __builtin_amdgcn_mfma_f32_16x16x32_bf16(qf1, rf1, la, 0, 0, 0);
        if (lc < 8) {
#pragma unroll
            for (int r = 0; r < 4; r++)
                lut[(row_w + lq*4 + r)*LUTS + lc] = la[r];
        }
    }

    // ---- prologue prefetch: K/V tile 0 + bucket tile 0 (i-row of symmetric table) ----
    const int srow = t >> 2, sd0 = (t & 3) * 16;
    u8s krg0, krg1, vrg0, vrg1;
    {
        const ushort_t* ks = kp + (size_t)srow * HD_ + sd0;
        krg0 = *(const u8s*)ks; krg1 = *(const u8s*)(ks + 8);
        const ushort_t* vs = vp + (size_t)srow * NPADV + sd0;
        vrg0 = *(const u8s*)vs; vrg1 = *(const u8s*)(vs + 8);
    }
    int myrow = i0 + row_w + lc; if (myrow > N_ - 1) myrow = N_ - 1;   // lane's Q-row (clamped)
    const unsigned char* bkrow = bucketT + (size_t)myrow * NPAD;
    const int lutbase = (row_w + lc) * LUTS;
    unsigned bk4[4];
#pragma unroll
    for (int t4 = 0; t4 < 4; t4++)
        bk4[t4] = *(const unsigned*)(bkrow + t4*16 + lq*4);

    v4f o[4];
    float lsum = 0.f;
#pragma unroll
    for (int dt = 0; dt < 4; dt++) o[dt] = (v4f){0.f, 0.f, 0.f, 0.f};

    for (int jt = 0; jt < 17; jt++) {
        const int j0 = jt * 64;
        __syncthreads();   // prev tile's frag reads (and prologue qf) done
        {
            ushort_t* kd = &Ks[srow*LDT + sd0];
            *(u8s*)kd = krg0; *(u8s*)(kd + 8) = krg1;
            ushort_t* vd = &Vs[srow*LDT + sd0];
            *(u8s*)vd = vrg0; *(u8s*)(vd + 8) = vrg1;
        }
        __syncthreads();   // staging visible

        // prefetch next tile's K/V + buckets (hidden behind this tile's compute)
        unsigned bk4n[4];
        if (jt < 16) {
            int gj = j0 + 64 + srow; if (gj > N_ - 1) gj = N_ - 1;
            const ushort_t* ks = kp + (size_t)gj * HD_ + sd0;
            krg0 = *(const u8s*)ks; krg1 = *(const u8s*)(ks + 8);
            const ushort_t* vs = vp + (size_t)srow * NPADV + (j0 + 64) + sd0;
            vrg0 = *(const u8s*)vs; vrg1 = *(const u8s*)(vs + 8);
#pragma unroll
            for (int t4 = 0; t4 < 4; t4++)
                bk4n[t4] = *(const unsigned*)(bkrow + j0 + 64 + t4*16 + lq*4);
        }

        // ---- S^T = K Q^T (swapped): acc[t4][r] = S[i=myrow][j=j0+t4*16+lq*4+r] ----
        v4f acc[4];
#pragma unroll
        for (int t4 = 0; t4 < 4; t4++) acc[t4] = (v4f){0.f, 0.f, 0.f, 0.f};
#pragma unroll
        for (int t4 = 0; t4 < 4; t4++) {
            s8bf kf0 = *(s8bf*)&Ks[(t4*16 + lc)*LDT + lq*8];
            s8bf kf1 = *(s8bf*)&Ks[(t4*16 + lc)*LDT + 32 + lq*8];
            acc[t4] = __builtin_amdgcn_mfma_f32_16x16x32_bf16(kf0, qf0, acc[t4], 0, 0, 0);
            acc[t4] = __builtin_amdgcn_mfma_f32_16x16x32_bf16(kf1, qf1, acc[t4], 0, 0, 0);
        }

        // ---- bias + exp (no max; logits provably small), per-lane row-local ----
        float pp[4][4];
#pragma unroll
        for (int t4 = 0; t4 < 4; t4++) {
#pragma unroll
            for (int r = 0; r < 4; r++) {
                int bk = (bk4[t4] >> (8*r)) & 0xFF;
                float sv = acc[t4][r] + lut[lutbase + bk];
                float p = __expf(sv);
                if (jt == 16 && (t4*16 + lq*4 + r) > 0) p = 0.f;   // tail: only j==1024 valid
                lsum += p;
                pp[t4][r] = p;
            }
        }
#pragma unroll
        for (int t4 = 0; t4 < 4; t4++) bk4[t4] = bk4n[t4];

        // ---- pack P row-wise: 4 consecutive j's -> one b64 write (was 16x b16) ----
#pragma unroll
        for (int t4 = 0; t4 < 4; t4++) {
            uint2 uu;
            uu.x = (unsigned)f2bf(pp[t4][0]) | ((unsigned)f2bf(pp[t4][1]) << 16);
            uu.y = (unsigned)f2bf(pp[t4][2]) | ((unsigned)f2bf(pp[t4][3]) << 16);
            *(uint2*)&Ps[(row_w + lc)*LDT + t4*16 + lq*4] = uu;
        }

        // ---- O += P V (P as A-frag: lane=row i — matches our storage; same-wave DS ordering) ----
        s8bf pf0 = *(s8bf*)&Ps[(row_w + lc)*LDT + lq*8];
        s8bf pf1 = *(s8bf*)&Ps[(row_w + lc)*LDT + 32 + lq*8];
#pragma unroll
        for (int dt = 0; dt < 4; dt++) {
            s8bf vf0 = *(s8bf*)&Vs[(dt*16 + lc)*LDT + lq*8];
            s8bf vf1 = *(s8bf*)&Vs[(dt*16 + lc)*LDT + 32 + lq*8];
            o[dt] = __builtin_amdgcn_mfma_f32_16x16x32_bf16(pf0, vf0, o[dt], 0, 0, 0);
            o[dt] = __builtin_amdgcn_mfma_f32_16x16x32_bf16(pf1, vf1, o[dt], 0, 0, 0);
        }
    }

    // ---- epilogue: lsum is per-lane partial for row i=myrow over j%16 in {lq*4..lq*4+3} ----
    lsum += __shfl_xor(lsum, 16);
    lsum += __shfl_xor(lsum, 32);          // lanes {lc,lc+16,lc+32,lc+48} now all hold total sum(row)
    if (lq == 0) lut[(row_w + lc)*LUTS + 8] = lsum;   // broadcast via lut col 8 (wave-private rows)
#pragma unroll
    for (int r = 0; r < 4; r++) {
        int i = i0 + row_w + lq*4 + r;
        if (i < N_) {
            float inv = 1.0f / lut[(row_w + lq*4 + r)*LUTS + 8];
#pragma unroll
            for (int dt = 0; dt < 4; dt++)
                ao[((size_t)(b*N_ + i))*C_ + hh*HD_ + dt*16 + lc] = f2bf(o[dt][r] * inv);
        }
    }
}

// ---------------- proj: out(8200x768) = aob @ wprojb^T + bias, f32 out ----------------
__global__ __launch_bounds__(256) void proj_kernel(
        const ushort_t* __restrict__ ab, const ushort_t* __restrict__ wb,
        const float* __restrict__ bias, float* __restrict__ out) {
    __shared__ __align__(16) ushort_t As0[128*64];
    __shared__ __align__(16) ushort_t Bs0[128*64];
    __shared__ __align__(16) ushort_t As1[128*64];
    __shared__ __align__(16) ushort_t Bs1[128*64];
    const int m0 = blockIdx.x * 128, c0 = blockIdx.y * 128;
    const int t = threadIdx.x;
    const int w = t >> 6, lane = t & 63, lc = lane & 15, lq = lane >> 4;
    const int wm = (w >> 1) * 64, wn = (w & 1) * 64;
    const int srow8 = w * 32 + (lane >> 3);
    const int gsw8  = (((lane & 7) ^ (lane >> 3)) & 7) * 8;

    v4f acc[4][4];
#pragma unroll
    for (int mt = 0; mt < 4; mt++)
#pragma unroll
        for (int nt = 0; nt < 4; nt++) acc[mt][nt] = (v4f){0.f, 0.f, 0.f, 0.f};

    auto STAGE = [&](ushort_t* Ad, ushort_t* Bd, int k0) {
#pragma unroll
        for (int i = 0; i < 4; i++) {
            int row = srow8 + i * 8;
            int m = m0 + row; if (m > NTOK - 1) m = NTOK - 1;
            GLOAD16(ab + (size_t)m * C_ + k0 + gsw8,           &Ad[(w*32 + i*8) * 64]);
            GLOAD16(wb + (size_t)(c0 + row) * C_ + k0 + gsw8,  &Bd[(w*32 + i*8) * 64]);
        }
    };
    auto COMPUTE = [&](const ushort_t* A, const ushort_t* B) {
#pragma unroll
        for (int kk = 0; kk < 64; kk += 32) {
            s8bf af[4], bf[4];
#pragma unroll
            for (int mt = 0; mt < 4; mt++)
                af[mt] = *(const s8bf*)&A[(wm + mt*16 + lc) * 64 + ((((kk>>3) + lq) ^ (lc & 7)) * 8)];
#pragma unroll
            for (int nt = 0; nt < 4; nt++)
                bf[nt] = *(const s8bf*)&B[(wn + nt*16 + lc) * 64 + ((((kk>>3) + lq) ^ (lc & 7)) * 8)];
#pragma unroll
            for (int mt = 0; mt < 4; mt++)
#pragma unroll
                for (int nt = 0; nt < 4; nt++)
                    acc[mt][nt] = __builtin_amdgcn_mfma_f32_16x16x32_bf16(af[mt], bf[nt], acc[mt][nt], 0, 0, 0);
        }
    };

    STAGE(As0, Bs0, 0);
#pragma unroll
    for (int it = 0; it < 6; ++it) {
        const int k0 = it * 128;
        if (k0 + 64 < C_) {
            STAGE(As1, Bs1, k0 + 64);
            asm volatile("s_waitcnt vmcnt(8)" ::: "memory");
        } else {
            asm volatile("s_waitcnt vmcnt(0)" ::: "memory");
        }
        SBAR();
        COMPUTE(As0, Bs0);
        SBAR();
        if (k0 + 128 < C_) {
            STAGE(As0, Bs0, k0 + 128);
            asm volatile("s_waitcnt vmcnt(8)" ::: "memory");
        } else {
            asm volatile("s_waitcnt vmcnt(0)" ::: "memory");
        }
        SBAR();
        COMPUTE(As1, Bs1);
        if (it < 5) SBAR();
    }

    float pb[4];
#pragma unroll
    for (int nt = 0; nt < 4; nt++) pb[nt] = bias[c0 + wn + nt*16 + lc];
#pragma unroll
    for (int mt = 0; mt < 4; mt++) {
#pragma unroll
        for (int r = 0; r < 4; r++) {
            int m = m0 + wm + mt*16 + lq*4 + r;
            if (m >= NTOK) continue;
#pragma unroll
            for (int nt = 0; nt < 4; nt++) {
                int c = c0 + wn + nt*16 + lc;
                out[(size_t)m * C_ + c] = acc[mt][nt][r] + pb[nt];
            }
        }
    }
}

extern "C" void kernel_launch(void* const* d_in, const int* in_sizes, int n_in,
                              void* d_out, int out_size, void* d_ws, size_t ws_size,
                              hipStream_t stream) {
    const float* x      = (const float*)d_in[0];
    const float* qkv_w  = (const float*)d_in[1];
    const float* proj_w = (const float*)d_in[2];
    const float* proj_b = (const float*)d_in[3];
    const float* rpe_w  = (const float*)d_in[4];
    float* out = (float*)d_out;

    char* ws = (char*)d_ws;
    ushort_t* xb   = (ushort_t*)(ws + XB_OFF_B);
    ushort_t* wqkv = (ushort_t*)(ws + WQKV_OFF_B);
    ushort_t* wprj = (ushort_t*)(ws + WPROJ_OFF_B);
    ushort_t* qb   = (ushort_t*)(ws + QB_OFF_B);
    ushort_t* kb   = (ushort_t*)(ws + KB_OFF_B);
    ushort_t* aob  = (ushort_t*)(ws + AOB_OFF_B);
    ushort_t* vt   = (ushort_t*)(ws + VT_OFF_B);
    unsigned char* bucketT = (unsigned char*)(ws + BUCKET_OFF_B);

    const int ncast = (NTOK*C_ + 3*C_*C_ + C_*C_) / 8;
    bucket_kernel<<<dim3((N_*NPAD + 255)/256), 256, 0, stream>>>(bucketT);
    cast_kernel<<<dim3((ncast + 255)/256), 256, 0, stream>>>(x, qkv_w, proj_w, xb, wqkv, wprj);
    qkv_kernel<<<dim3(65, 18), 256, 0, stream>>>(xb, wqkv, qb, kb, vt);
    attn_kernel<<<dim3(96, 17), 256, 0, stream>>>(qb, kb, vt, rpe_w, bucketT, aob);
    proj_kernel<<<dim3(65, 6), 256, 0, stream>>>(aob, wprj, proj_b, out);
}

// Round 7
// 244.088 us; speedup vs baseline: 1.0629x; 1.0311x over previous
//
#include <hip/hip_runtime.h>
#include <math.h>

#define B_    8
#define N_    1025
#define H_    12
#define HD_   64
#define C_    768
#define BH_   (B_*H_)
#define NTOK  (B_*N_)          // 8200
#define SCALE 0.125f
#define NPAD  1092             // bucketT row stride (mult of 4); table is SYMMETRIC: [a][b]=bucket(a,b)
#define NPADV 1088             // vt row stride (17*64)

#define QKV_ELEMS (BH_*N_*HD_)         // 6,297,600

// ws layout (bytes)
#define XB_OFF_B     ((size_t)0)
#define WQKV_OFF_B   (XB_OFF_B + (size_t)NTOK*C_*2)
#define WPROJ_OFF_B  (WQKV_OFF_B + (size_t)3*C_*C_*2)
#define QB_OFF_B     (WPROJ_OFF_B + (size_t)C_*C_*2)
#define KB_OFF_B     (QB_OFF_B + (size_t)QKV_ELEMS*2)
#define AOB_OFF_B    (KB_OFF_B + (size_t)QKV_ELEMS*2)
#define VT_OFF_B     (AOB_OFF_B + (size_t)QKV_ELEMS*2)
#define BUCKET_OFF_B (VT_OFF_B + (size_t)BH_*HD_*NPADV*2)

typedef __attribute__((ext_vector_type(8))) short s8bf;
typedef __attribute__((ext_vector_type(8))) unsigned short u8s;
typedef __attribute__((ext_vector_type(4))) float v4f;
typedef unsigned short ushort_t;

// async global -> LDS, 16B per lane. LDS dest must be wave-uniform base
// (HW writes base + lane*16); global src is per-lane.
#define GLOAD16(gp, lp) __builtin_amdgcn_global_load_lds( \
    (const __attribute__((address_space(1))) unsigned int*)(gp), \
    (__attribute__((address_space(3))) unsigned int*)(lp), 16, 0, 0)

// raw workgroup barrier with compiler memory fence (no vmcnt drain, unlike __syncthreads)
#define SBAR() do { \
    __builtin_amdgcn_sched_barrier(0); \
    asm volatile("s_barrier" ::: "memory"); \
    __builtin_amdgcn_sched_barrier(0); \
} while (0)

// hand-RNE f32->bf16 (KEEP: v_cvt_pk_bf16_f32 asm path failed absmax in R3 —
// rounding-mode bias accumulated coherently across the bf16 pipeline)
__device__ __forceinline__ unsigned short f2bf(float x) {
    union { float f; unsigned u; } v; v.f = x;
    unsigned r = v.u + 0x7FFFu + ((v.u >> 16) & 1u);
    return (unsigned short)(r >> 16);
}

// ---- bucketT[a][b] = bucket(a,b), integer-exact & SYMMETRIC: {d2=0:0, d2<=2:1, d2<=12:2, else 3}, cls:7 ----
__global__ void bucket_kernel(unsigned char* __restrict__ bucketT) {
    int tid = blockIdx.x * 256 + threadIdx.x;
    if (tid >= N_ * NPAD) return;
    unsigned ut = (unsigned)tid;
    int j = ut / (unsigned)NPAD, i = ut % (unsigned)NPAD;
    if (i >= N_) i = N_ - 1;
    int bk;
    if (i < 1 || j < 1) {
        bk = 7;
    } else {
        int pi = i - 1, pj = j - 1;
        int dy = (pi >> 5) - (pj >> 5);
        int dx = (pi & 31) - (pj & 31);
        int d2 = dy*dy + dx*dx;
        bk = (d2 == 0) ? 0 : ((d2 <= 2) ? 1 : ((d2 <= 12) ? 2 : 3));
    }
    bucketT[tid] = (unsigned char)bk;
}

// ---------------- fused f32 -> bf16 cast (x, qkv_w, proj_w) ----------------
__global__ __launch_bounds__(256) void cast_kernel(
        const float* __restrict__ x, const float* __restrict__ w1,
        const float* __restrict__ w2,
        ushort_t* __restrict__ xb, ushort_t* __restrict__ w1b,
        ushort_t* __restrict__ w2b) {
    const int NX = NTOK * C_ / 8, NW1 = 3 * C_ * C_ / 8, NW2 = C_ * C_ / 8;
    int g = blockIdx.x * 256 + threadIdx.x;
    const float* src; ushort_t* dst; int idx;
    if (g < NX)                 { src = x;  dst = xb;  idx = g; }
    else if (g < NX + NW1)      { src = w1; dst = w1b; idx = g - NX; }
    else if (g < NX + NW1 + NW2){ src = w2; dst = w2b; idx = g - NX - NW1; }
    else return;
    size_t off = (size_t)idx * 8;
    float4 a = *(const float4*)(src + off);
    float4 c = *(const float4*)(src + off + 4);
    __align__(16) ushort_t h[8] = {f2bf(a.x), f2bf(a.y), f2bf(a.z), f2bf(a.w),
                                   f2bf(c.x), f2bf(c.y), f2bf(c.z), f2bf(c.w)};
    *(u8s*)(dst + off) = *(u8s*)h;
}

// ---------------- bf16 MFMA GEMM: 128x128 tile, BK=64, DOUBLE-BUFFERED global_load_lds ----------------
__global__ __launch_bounds__(256) void qkv_kernel(
        const ushort_t* __restrict__ xb, const ushort_t* __restrict__ wb,
        ushort_t* __restrict__ qb, ushort_t* __restrict__ kb, ushort_t* __restrict__ vt) {
    __shared__ __align__(16) ushort_t As0[128*64];
    __shared__ __align__(16) ushort_t Bs0[128*64];
    __shared__ __align__(16) ushort_t As1[128*64];
    __shared__ __align__(16) ushort_t Bs1[128*64];
    const int m0 = blockIdx.x * 128, c0 = blockIdx.y * 128;
    const int t = threadIdx.x;
    const int w = t >> 6, lane = t & 63, lc = lane & 15, lq = lane >> 4;
    const int wm = (w >> 1) * 64, wn = (w & 1) * 64;
    const int srow8 = w * 32 + (lane >> 3);                    // + i*8 = row within tile
    const int gsw8  = (((lane & 7) ^ (lane >> 3)) & 7) * 8;    // swizzled source col (ushorts)

    v4f acc[4][4];
#pragma unroll
    for (int mt = 0; mt < 4; mt++)
#pragma unroll
        for (int nt = 0; nt < 4; nt++) acc[mt][nt] = (v4f){0.f, 0.f, 0.f, 0.f};

    auto STAGE = [&](ushort_t* Ad, ushort_t* Bd, int k0) {
#pragma unroll
        for (int i = 0; i < 4; i++) {
            int row = srow8 + i * 8;
            int m = m0 + row; if (m > NTOK - 1) m = NTOK - 1;   // clamp: dup reads, rows masked in epilogue
            GLOAD16(xb + (size_t)m * C_ + k0 + gsw8,           &Ad[(w*32 + i*8) * 64]);
            GLOAD16(wb + (size_t)(c0 + row) * C_ + k0 + gsw8,  &Bd[(w*32 + i*8) * 64]);
        }
    };
    auto COMPUTE = [&](const ushort_t* A, const ushort_t* B) {
#pragma unroll
        for (int kk = 0; kk < 64; kk += 32) {
            s8bf af[4], bf[4];
#pragma unroll
            for (int mt = 0; mt < 4; mt++)
                af[mt] = *(const s8bf*)&A[(wm + mt*16 + lc) * 64 + ((((kk>>3) + lq) ^ (lc & 7)) * 8)];
#pragma unroll
            for (int nt = 0; nt < 4; nt++)
                bf[nt] = *(const s8bf*)&B[(wn + nt*16 + lc) * 64 + ((((kk>>3) + lq) ^ (lc & 7)) * 8)];
#pragma unroll
            for (int mt = 0; mt < 4; mt++)
#pragma unroll
                for (int nt = 0; nt < 4; nt++)
                    acc[mt][nt] = __builtin_amdgcn_mfma_f32_16x16x32_bf16(af[mt], bf[nt], acc[mt][nt], 0, 0, 0);
        }
    };

    STAGE(As0, Bs0, 0);
#pragma unroll
    for (int it = 0; it < 6; ++it) {
        const int k0 = it * 128;
        if (k0 + 64 < C_) {
            STAGE(As1, Bs1, k0 + 64);
            asm volatile("s_waitcnt vmcnt(8)" ::: "memory");
        } else {
            asm volatile("s_waitcnt vmcnt(0)" ::: "memory");
        }
        SBAR();
        COMPUTE(As0, Bs0);
        SBAR();
        if (k0 + 128 < C_) {
            STAGE(As0, Bs0, k0 + 128);
            asm volatile("s_waitcnt vmcnt(8)" ::: "memory");
        } else {
            asm volatile("s_waitcnt vmcnt(0)" ::: "memory");
        }
        SBAR();
        COMPUTE(As1, Bs1);
        if (it < 5) SBAR();
    }

#pragma unroll
    for (int mt = 0; mt < 4; mt++) {
#pragma unroll
        for (int r = 0; r < 4; r++) {
            int m = m0 + wm + mt*16 + lq*4 + r;
            if (m >= NTOK) continue;
            unsigned um = (unsigned)m;
            int b = um / (unsigned)N_, n = um % (unsigned)N_;
#pragma unroll
            for (int nt = 0; nt < 4; nt++) {
                int c = c0 + wn + nt*16 + lc;
                int comp = c / C_, rem = c % C_;
                int h = rem >> 6, d0 = rem & 63;
                float val = acc[mt][nt][r] * ((comp == 0) ? SCALE : 1.0f);
                if (comp == 2) {
                    vt[((size_t)((b*H_ + h)*HD_ + d0))*NPADV + n] = f2bf(val);
                } else {
                    ushort_t* dst = (comp == 0) ? qb : kb;
                    dst[((size_t)((b*H_ + h)*N_ + n))*HD_ + d0] = f2bf(val);
                }
            }
        }
    }
}

// ---------------- attention: swapped QK^T + K-slot permutation => P stays in registers ----------------
// K row j stored at LDS slot sigma(j): j=32d+8a+4b+c -> slot=32d+16b+4a+c (bijection).
// Linear frag reads (t4*16+lc) then yield acc[t4][r] = S[i=myrow][j=32(t4>>1)+4(t4&1)+8lq+r],
// so {acc0,acc1} packs straight into PV A-frag pf0 (j 0..31) and {acc2,acc3} into pf1 —
// NO P LDS round-trip. rpe prologue aliases onto Ks; Ps eliminated (LDS 30K->21K).
#define LDT  72
#define LUTS 9

__global__ __launch_bounds__(256) void attn_kernel(
        const ushort_t* __restrict__ qb, const ushort_t* __restrict__ kb,
        const ushort_t* __restrict__ vt, const float* __restrict__ rpe,
        const unsigned char* __restrict__ bucketT, ushort_t* __restrict__ ao) {
    __shared__ __align__(16) ushort_t Ks[64*LDT];   // prologue alias rows 0..15: rpe^T
    __shared__ __align__(16) ushort_t Vs[64*LDT];   // prologue alias: Q tile; loop: V^T Vs[d][j]
    __shared__ float lut[64*LUTS];                  // col 8: lsum broadcast (epilogue)

    const int bh = blockIdx.x, it = blockIdx.y;     // bh-major: all i-tiles of bh on one XCD
    const int b  = bh / H_, hh = bh % H_;
    const int i0 = it * 64;
    const int t  = threadIdx.x;
    const int w  = t >> 6, lane = t & 63, lc = lane & 15, lq = lane >> 4;
    const int row_w = w * 16;                       // wave strip (16 rows)

    const ushort_t* qp = qb + (size_t)bh * N_ * HD_;
    const ushort_t* kp = kb + (size_t)bh * N_ * HD_;
    const ushort_t* vp = vt + (size_t)bh * HD_ * NPADV;

    // ---- stage Q into Vs (zero rows >= N) ----
    {
        int row = t >> 2, d0 = (t & 3) * 16;
        int gi = i0 + row;
        u8s h0 = (u8s)0, h1 = (u8s)0;
        if (gi < N_) {
            h0 = *(const u8s*)(qp + (size_t)gi * HD_ + d0);
            h1 = *(const u8s*)(qp + (size_t)gi * HD_ + d0 + 8);
        }
        *(u8s*)&Vs[row*LDT + d0]     = h0;
        *(u8s*)&Vs[row*LDT + d0 + 8] = h1;
    }
    // ---- stage rpe^T into Ks rows 0..7 (row=m, col=d), zero rows 8..15 ----
    if (t < 64) {
        float4 r0 = *(const float4*)(rpe + t*8);
        float4 r1 = *(const float4*)(rpe + t*8 + 4);
        Ks[0*LDT + t] = f2bf(r0.x); Ks[1*LDT + t] = f2bf(r0.y);
        Ks[2*LDT + t] = f2bf(r0.z); Ks[3*LDT + t] = f2bf(r0.w);
        Ks[4*LDT + t] = f2bf(r1.x); Ks[5*LDT + t] = f2bf(r1.y);
        Ks[6*LDT + t] = f2bf(r1.z); Ks[7*LDT + t] = f2bf(r1.w);
    } else if (t < 128) {
        int idx = t - 64;
        int m = 8 + (idx >> 3), c = (idx & 7) * 8;
        *(u8s*)&Ks[m*LDT + c] = (u8s)0;
    }
    __syncthreads();

    // ---- Q A-fragments (held all K-tiles) ----
    s8bf qf0 = *(s8bf*)&Vs[(row_w + lc)*LDT + lq*8];
    s8bf qf1 = *(s8bf*)&Vs[(row_w + lc)*LDT + 32 + lq*8];

    // ---- lut = Q @ rpe via MFMA (wave-private rows; rf reads precede loop's first barrier) ----
    {
        s8bf rf0 = *(s8bf*)&Ks[lc*LDT + lq*8];
        s8bf rf1 = *(s8bf*)&Ks[lc*LDT + 32 + lq*8];
        v4f la = (v4f){0.f, 0.f, 0.f, 0.f};
        la = __builtin_amdgcn_mfma_f32_16x16x32_bf16(qf0, rf0, la, 0, 0, 0);
        la = __builtin_amdgcn_mfma_f32_16x16x32_bf16(qf1, rf1, la, 0, 0, 0);
        if (lc < 8) {
#pragma unroll
            for (int r = 0; r < 4; r++)
                lut[(row_w + lq*4 + r)*LUTS + lc] = la[r];
        }
    }

    // ---- prologue prefetch: K/V tile 0 + bucket tile 0 (i-row of symmetric table) ----
    const int srow = t >> 2, sd0 = (t & 3) * 16;
    // K staging slot: sigma(srow) — j=32d+8a+4b+c -> slot=32d+16b+4a+c
    const int kslot = ((srow >> 5) * 2 + ((srow >> 2) & 1)) * 16 + ((srow >> 3) & 3) * 4 + (srow & 3);
    u8s krg0, krg1, vrg0, vrg1;
    {
        const ushort_t* ks = kp + (size_t)srow * HD_ + sd0;
        krg0 = *(const u8s*)ks; krg1 = *(const u8s*)(ks + 8);
        const ushort_t* vs = vp + (size_t)srow * NPADV + sd0;
        vrg0 = *(const u8s*)vs; vrg1 = *(const u8s*)(vs + 8);
    }
    int myrow = i0 + row_w + lc; if (myrow > N_ - 1) myrow = N_ - 1;   // lane's Q-row (clamped)
    const unsigned char* bkrow = bucketT + (size_t)myrow * NPAD;
    const int lutbase = (row_w + lc) * LUTS;
    // per-lane j base within tile for quadrant t4: 32*(t4>>1) + 4*(t4&1) + 8*lq
    const int jb0 = 8*lq, jb1 = 8*lq + 4, jb2 = 8*lq + 32, jb3 = 8*lq + 36;
    unsigned bk4[4];
    bk4[0] = *(const unsigned*)(bkrow + jb0);
    bk4[1] = *(const unsigned*)(bkrow + jb1);
    bk4[2] = *(const unsigned*)(bkrow + jb2);
    bk4[3] = *(const unsigned*)(bkrow + jb3);

    v4f o[4];
    float lsum = 0.f;
#pragma unroll
    for (int dt = 0; dt < 4; dt++) o[dt] = (v4f){0.f, 0.f, 0.f, 0.f};

    for (int jt = 0; jt < 17; jt++) {
        const int j0 = jt * 64;
        __syncthreads();   // prev tile's frag reads (and prologue qf/rf) done
        {
            ushort_t* kd = &Ks[kslot*LDT + sd0];
            *(u8s*)kd = krg0; *(u8s*)(kd + 8) = krg1;
            ushort_t* vd = &Vs[srow*LDT + sd0];
            *(u8s*)vd = vrg0; *(u8s*)(vd + 8) = vrg1;
        }
        __syncthreads();   // staging visible

        // prefetch next tile's K/V + buckets (hidden behind this tile's compute)
        unsigned bk4n[4];
        if (jt < 16) {
            int gj = j0 + 64 + srow; if (gj > N_ - 1) gj = N_ - 1;
            const ushort_t* ks = kp + (size_t)gj * HD_ + sd0;
            krg0 = *(const u8s*)ks; krg1 = *(const u8s*)(ks + 8);
            const ushort_t* vs = vp + (size_t)srow * NPADV + (j0 + 64) + sd0;
            vrg0 = *(const u8s*)vs; vrg1 = *(const u8s*)(vs + 8);
            bk4n[0] = *(const unsigned*)(bkrow + j0 + 64 + jb0);
            bk4n[1] = *(const unsigned*)(bkrow + j0 + 64 + jb1);
            bk4n[2] = *(const unsigned*)(bkrow + j0 + 64 + jb2);
            bk4n[3] = *(const unsigned*)(bkrow + j0 + 64 + jb3);
        }

        // ---- S^T = K Q^T (swapped, slot-permuted): acc[t4][r] = S[myrow][j0 + jb{t4} + r] ----
        v4f acc[4];
#pragma unroll
        for (int t4 = 0; t4 < 4; t4++) acc[t4] = (v4f){0.f, 0.f, 0.f, 0.f};
#pragma unroll
        for (int t4 = 0; t4 < 4; t4++) {
            s8bf kf0 = *(s8bf*)&Ks[(t4*16 + lc)*LDT + lq*8];
            s8bf kf1 = *(s8bf*)&Ks[(t4*16 + lc)*LDT + 32 + lq*8];
            acc[t4] = __builtin_amdgcn_mfma_f32_16x16x32_bf16(kf0, qf0, acc[t4], 0, 0, 0);
            acc[t4] = __builtin_amdgcn_mfma_f32_16x16x32_bf16(kf1, qf1, acc[t4], 0, 0, 0);
        }

        // ---- bias + exp (no max; logits provably small), per-lane row-local ----
        float pp[4][4];
        const int jbs[4] = {jb0, jb1, jb2, jb3};
#pragma unroll
        for (int t4 = 0; t4 < 4; t4++) {
#pragma unroll
            for (int r = 0; r < 4; r++) {
                int bk = (bk4[t4] >> (8*r)) & 0xFF;
                float sv = acc[t4][r] + lut[lutbase + bk];
                float p = __expf(sv);
                if (jt == 16 && (jbs[t4] + r) > 0) p = 0.f;   // tail: only j==1024 valid
                lsum += p;
                pp[t4][r] = p;
            }
        }
#pragma unroll
        for (int t4 = 0; t4 < 4; t4++) bk4[t4] = bk4n[t4];

        // ---- pack P directly into PV A-frags (registers only; no LDS) ----
        __align__(16) ushort_t ph[16] = {
            f2bf(pp[0][0]), f2bf(pp[0][1]), f2bf(pp[0][2]), f2bf(pp[0][3]),
            f2bf(pp[1][0]), f2bf(pp[1][1]), f2bf(pp[1][2]), f2bf(pp[1][3]),
            f2bf(pp[2][0]), f2bf(pp[2][1]), f2bf(pp[2][2]), f2bf(pp[2][3]),
            f2bf(pp[3][0]), f2bf(pp[3][1]), f2bf(pp[3][2]), f2bf(pp[3][3])};
        s8bf pf0 = *(s8bf*)&ph[0];
        s8bf pf1 = *(s8bf*)&ph[8];

        // ---- O += P V ----
#pragma unroll
        for (int dt = 0; dt < 4; dt++) {
            s8bf vf0 = *(s8bf*)&Vs[(dt*16 + lc)*LDT + lq*8];
            s8bf vf1 = *(s8bf*)&Vs[(dt*16 + lc)*LDT + 32 + lq*8];
            o[dt] = __builtin_amdgcn_mfma_f32_16x16x32_bf16(pf0, vf0, o[dt], 0, 0, 0);
            o[dt] = __builtin_amdgcn_mfma_f32_16x16x32_bf16(pf1, vf1, o[dt], 0, 0, 0);
        }
    }

    // ---- epilogue: lsum partial over this lane's j-subset; reduce over lq, bcast via lut col 8 ----
    lsum += __shfl_xor(lsum, 16);
    lsum += __shfl_xor(lsum, 32);          // lanes {lc,lc+16,lc+32,lc+48} hold total sum(row)
    if (lq == 0) lut[(row_w + lc)*LUTS + 8] = lsum;
    __builtin_amdgcn_s_waitcnt(0);          // lgkm drain before same-wave read (cheap, wave-private rows)
#pragma unroll
    for (int r = 0; r < 4; r++) {
        int i = i0 + row_w + lq*4 + r;
        if (i < N_) {
            float inv = 1.0f / lut[(row_w + lq*4 + r)*LUTS + 8];
#pragma unroll
            for (int dt = 0; dt < 4; dt++)
                ao[((size_t)(b*N_ + i))*C_ + hh*HD_ + dt*16 + lc] = f2bf(o[dt][r] * inv);
        }
    }
}

// ---------------- proj: out(8200x768) = aob @ wprojb^T + bias, f32 out ----------------
__global__ __launch_bounds__(256) void proj_kernel(
        const ushort_t* __restrict__ ab, const ushort_t* __restrict__ wb,
        const float* __restrict__ bias, float* __restrict__ out) {
    __shared__ __align__(16) ushort_t As0[128*64];
    __shared__ __align__(16) ushort_t Bs0[128*64];
    __shared__ __align__(16) ushort_t As1[128*64];
    __shared__ __align__(16) ushort_t Bs1[128*64];
    const int m0 = blockIdx.x * 128, c0 = blockIdx.y * 128;
    const int t = threadIdx.x;
    const int w = t >> 6, lane = t & 63, lc = lane & 15, lq = lane >> 4;
    const int wm = (w >> 1) * 64, wn = (w & 1) * 64;
    const int srow8 = w * 32 + (lane >> 3);
    const int gsw8  = (((lane & 7) ^ (lane >> 3)) & 7) * 8;

    v4f acc[4][4];
#pragma unroll
    for (int mt = 0; mt < 4; mt++)
#pragma unroll
        for (int nt = 0; nt < 4; nt++) acc[mt][nt] = (v4f){0.f, 0.f, 0.f, 0.f};

    auto STAGE = [&](ushort_t* Ad, ushort_t* Bd, int k0) {
#pragma unroll
        for (int i = 0; i < 4; i++) {
            int row = srow8 + i * 8;
            int m = m0 + row; if (m > NTOK - 1) m = NTOK - 1;
            GLOAD16(ab + (size_t)m * C_ + k0 + gsw8,           &Ad[(w*32 + i*8) * 64]);
            GLOAD16(wb + (size_t)(c0 + row) * C_ + k0 + gsw8,  &Bd[(w*32 + i*8) * 64]);
        }
    };
    auto COMPUTE = [&](const ushort_t* A, const ushort_t* B) {
#pragma unroll
        for (int kk = 0; kk < 64; kk += 32) {
            s8bf af[4], bf[4];
#pragma unroll
            for (int mt = 0; mt < 4; mt++)
                af[mt] = *(const s8bf*)&A[(wm + mt*16 + lc) * 64 + ((((kk>>3) + lq) ^ (lc & 7)) * 8)];
#pragma unroll
            for (int nt = 0; nt < 4; nt++)
                bf[nt] = *(const s8bf*)&B[(wn + nt*16 + lc) * 64 + ((((kk>>3) + lq) ^ (lc & 7)) * 8)];
#pragma unroll
            for (int mt = 0; mt < 4; mt++)
#pragma unroll
                for (int nt = 0; nt < 4; nt++)
                    acc[mt][nt] = __builtin_amdgcn_mfma_f32_16x16x32_bf16(af[mt], bf[nt], acc[mt][nt], 0, 0, 0);
        }
    };

    STAGE(As0, Bs0, 0);
#pragma unroll
    for (int it = 0; it < 6; ++it) {
        const int k0 = it * 128;
        if (k0 + 64 < C_) {
            STAGE(As1, Bs1, k0 + 64);
            asm volatile("s_waitcnt vmcnt(8)" ::: "memory");
        } else {
            asm volatile("s_waitcnt vmcnt(0)" ::: "memory");
        }
        SBAR();
        COMPUTE(As0, Bs0);
        SBAR();
        if (k0 + 128 < C_) {
            STAGE(As0, Bs0, k0 + 128);
            asm volatile("s_waitcnt vmcnt(8)" ::: "memory");
        } else {
            asm volatile("s_waitcnt vmcnt(0)" ::: "memory");
        }
        SBAR();
        COMPUTE(As1, Bs1);
        if (it < 5) SBAR();
    }

    float pb[4];
#pragma unroll
    for (int nt = 0; nt < 4; nt++) pb[nt] = bias[c0 + wn + nt*16 + lc];
#pragma unroll
    for (int mt = 0; mt < 4; mt++) {
#pragma unroll
        for (int r = 0; r < 4; r++) {
            int m = m0 + wm + mt*16 + lq*4 + r;
            if (m >= NTOK) continue;
#pragma unroll
            for (int nt = 0; nt < 4; nt++) {
                int c = c0 + wn + nt*16 + lc;
                out[(size_t)m * C_ + c] = acc[mt][nt][r] + pb[nt];
            }
        }
    }
}

extern "C" void kernel_launch(void* const* d_in, const int* in_sizes, int n_in,
                              void* d_out, int out_size, void* d_ws, size_t ws_size,
                              hipStream_t stream) {
    const float* x      = (const float*)d_in[0];
    const float* qkv_w  = (const float*)d_in[1];
    const float* proj_w = (const float*)d_in[2];
    const float* proj_b = (const float*)d_in[3];
    const float* rpe_w  = (const float*)d_in[4];
    float* out = (float*)d_out;

    char* ws = (char*)d_ws;
    ushort_t* xb   = (ushort_t*)(ws + XB_OFF_B);
    ushort_t* wqkv = (ushort_t*)(ws + WQKV_OFF_B);
    ushort_t* wprj = (ushort_t*)(ws + WPROJ_OFF_B);
    ushort_t* qb   = (ushort_t*)(ws + QB_OFF_B);
    ushort_t* kb   = (ushort_t*)(ws + KB_OFF_B);
    ushort_t* aob  = (ushort_t*)(ws + AOB_OFF_B);
    ushort_t* vt   = (ushort_t*)(ws + VT_OFF_B);
    unsigned char* bucketT = (unsigned char*)(ws + BUCKET_OFF_B);

    const int ncast = (NTOK*C_ + 3*C_*C_ + C_*C_) / 8;
    bucket_kernel<<<dim3((N_*NPAD + 255)/256), 256, 0, stream>>>(bucketT);
    cast_kernel<<<dim3((ncast + 255)/256), 256, 0, stream>>>(x, qkv_w, proj_w, xb, wqkv, wprj);
    qkv_kernel<<<dim3(65, 18), 256, 0, stream>>>(xb, wqkv, qb, kb, vt);
    attn_kernel<<<dim3(96, 17), 256, 0, stream>>>(qb, kb, vt, rpe_w, bucketT, aob);
    proj_kernel<<<dim3(65, 6), 256, 0, stream>>>(aob, wprj, proj_b, out);
}

// Round 8
// 231.144 us; speedup vs baseline: 1.1224x; 1.0560x over previous
//
#include <hip/hip_runtime.h>
#include <math.h>

#define B_    8
#define N_    1025
#define H_    12
#define HD_   64
#define C_    768
#define BH_   (B_*H_)
#define NTOK  (B_*N_)          // 8200
#define SCALE 0.125f
#define NPAD  1092             // bucketT row stride (mult of 4); table is SYMMETRIC: [a][b]=bucket(a,b)
#define NPADV 1088             // vt row stride (17*64)

#define QKV_ELEMS (BH_*N_*HD_)         // 6,297,600

// ws layout (bytes)
#define XB_OFF_B     ((size_t)0)
#define WQKV_OFF_B   (XB_OFF_B + (size_t)NTOK*C_*2)
#define WPROJ_OFF_B  (WQKV_OFF_B + (size_t)3*C_*C_*2)
#define QB_OFF_B     (WPROJ_OFF_B + (size_t)C_*C_*2)
#define KB_OFF_B     (QB_OFF_B + (size_t)QKV_ELEMS*2)
#define AOB_OFF_B    (KB_OFF_B + (size_t)QKV_ELEMS*2)
#define VT_OFF_B     (AOB_OFF_B + (size_t)QKV_ELEMS*2)
#define BUCKET_OFF_B (VT_OFF_B + (size_t)BH_*HD_*NPADV*2)

typedef __attribute__((ext_vector_type(8))) short s8bf;
typedef __attribute__((ext_vector_type(8))) unsigned short u8s;
typedef __attribute__((ext_vector_type(4))) float v4f;
typedef unsigned short ushort_t;

// async global -> LDS, 16B per lane. LDS dest must be wave-uniform base
// (HW writes base + lane*16); global src is per-lane.
#define GLOAD16(gp, lp) __builtin_amdgcn_global_load_lds( \
    (const __attribute__((address_space(1))) unsigned int*)(gp), \
    (__attribute__((address_space(3))) unsigned int*)(lp), 16, 0, 0)

// raw workgroup barrier with compiler memory fence (no vmcnt drain, unlike __syncthreads)
#define SBAR() do { \
    __builtin_amdgcn_sched_barrier(0); \
    asm volatile("s_barrier" ::: "memory"); \
    __builtin_amdgcn_sched_barrier(0); \
} while (0)

// hand-RNE f32->bf16 (KEEP: v_cvt_pk_bf16_f32 asm path failed absmax in R3 —
// rounding-mode bias accumulated coherently across the bf16 pipeline)
__device__ __forceinline__ unsigned short f2bf(float x) {
    union { float f; unsigned u; } v; v.f = x;
    unsigned r = v.u + 0x7FFFu + ((v.u >> 16) & 1u);
    return (unsigned short)(r >> 16);
}

// ---- bucketT[a][b] = bucket(a,b), integer-exact & SYMMETRIC: {d2=0:0, d2<=2:1, d2<=12:2, else 3}, cls:7 ----
__global__ void bucket_kernel(unsigned char* __restrict__ bucketT) {
    int tid = blockIdx.x * 256 + threadIdx.x;
    if (tid >= N_ * NPAD) return;
    unsigned ut = (unsigned)tid;
    int j = ut / (unsigned)NPAD, i = ut % (unsigned)NPAD;
    if (i >= N_) i = N_ - 1;
    int bk;
    if (i < 1 || j < 1) {
        bk = 7;
    } else {
        int pi = i - 1, pj = j - 1;
        int dy = (pi >> 5) - (pj >> 5);
        int dx = (pi & 31) - (pj & 31);
        int d2 = dy*dy + dx*dx;
        bk = (d2 == 0) ? 0 : ((d2 <= 2) ? 1 : ((d2 <= 12) ? 2 : 3));
    }
    bucketT[tid] = (unsigned char)bk;
}

// ---------------- fused f32 -> bf16 cast (x, qkv_w, proj_w) ----------------
__global__ __launch_bounds__(256) void cast_kernel(
        const float* __restrict__ x, const float* __restrict__ w1,
        const float* __restrict__ w2,
        ushort_t* __restrict__ xb, ushort_t* __restrict__ w1b,
        ushort_t* __restrict__ w2b) {
    const int NX = NTOK * C_ / 8, NW1 = 3 * C_ * C_ / 8, NW2 = C_ * C_ / 8;
    int g = blockIdx.x * 256 + threadIdx.x;
    const float* src; ushort_t* dst; int idx;
    if (g < NX)                 { src = x;  dst = xb;  idx = g; }
    else if (g < NX + NW1)      { src = w1; dst = w1b; idx = g - NX; }
    else if (g < NX + NW1 + NW2){ src = w2; dst = w2b; idx = g - NX - NW1; }
    else return;
    size_t off = (size_t)idx * 8;
    float4 a = *(const float4*)(src + off);
    float4 c = *(const float4*)(src + off + 4);
    __align__(16) ushort_t h[8] = {f2bf(a.x), f2bf(a.y), f2bf(a.z), f2bf(a.w),
                                   f2bf(c.x), f2bf(c.y), f2bf(c.z), f2bf(c.w)};
    *(u8s*)(dst + off) = *(u8s*)h;
}

// ---------------- bf16 MFMA GEMM: 128x128 tile, BK=64, DOUBLE-BUFFERED global_load_lds ----------------
// T1 XCD swizzle (bijective, m204): linear id L -> xcd=L%8 owns contiguous wg-range,
// enumerated c0-fastest => each XCD's L2 holds an A-stripe (~1.6MB, reused 18x) + full B
// (3.5MB, reused 8x). Was: round-robin scattered both panels across all 8 L2s (126MB fetch).
__global__ __launch_bounds__(256) void qkv_kernel(
        const ushort_t* __restrict__ xb, const ushort_t* __restrict__ wb,
        ushort_t* __restrict__ qb, ushort_t* __restrict__ kb, ushort_t* __restrict__ vt) {
    __shared__ __align__(16) ushort_t As0[128*64];
    __shared__ __align__(16) ushort_t Bs0[128*64];
    __shared__ __align__(16) ushort_t As1[128*64];
    __shared__ __align__(16) ushort_t Bs1[128*64];
    // bijective XCD remap: nwg=1170, q=146, r=2
    const int L = blockIdx.x + blockIdx.y * 65;
    const int xcd = L & 7, idx = L >> 3;
    const int wg = (xcd < 2 ? xcd * 147 : 2 * 147 + (xcd - 2) * 146) + idx;
    const int m0 = (wg / 18) * 128, c0 = (wg % 18) * 128;
    const int t = threadIdx.x;
    const int w = t >> 6, lane = t & 63, lc = lane & 15, lq = lane >> 4;
    const int wm = (w >> 1) * 64, wn = (w & 1) * 64;
    const int srow8 = w * 32 + (lane >> 3);                    // + i*8 = row within tile
    const int gsw8  = (((lane & 7) ^ (lane >> 3)) & 7) * 8;    // swizzled source col (ushorts)

    v4f acc[4][4];
#pragma unroll
    for (int mt = 0; mt < 4; mt++)
#pragma unroll
        for (int nt = 0; nt < 4; nt++) acc[mt][nt] = (v4f){0.f, 0.f, 0.f, 0.f};

    auto STAGE = [&](ushort_t* Ad, ushort_t* Bd, int k0) {
#pragma unroll
        for (int i = 0; i < 4; i++) {
            int row = srow8 + i * 8;
            int m = m0 + row; if (m > NTOK - 1) m = NTOK - 1;   // clamp: dup reads, rows masked in epilogue
            GLOAD16(xb + (size_t)m * C_ + k0 + gsw8,           &Ad[(w*32 + i*8) * 64]);
            GLOAD16(wb + (size_t)(c0 + row) * C_ + k0 + gsw8,  &Bd[(w*32 + i*8) * 64]);
        }
    };
    auto COMPUTE = [&](const ushort_t* A, const ushort_t* B) {
#pragma unroll
        for (int kk = 0; kk < 64; kk += 32) {
            s8bf af[4], bf[4];
#pragma unroll
            for (int mt = 0; mt < 4; mt++)
                af[mt] = *(const s8bf*)&A[(wm + mt*16 + lc) * 64 + ((((kk>>3) + lq) ^ (lc & 7)) * 8)];
#pragma unroll
            for (int nt = 0; nt < 4; nt++)
                bf[nt] = *(const s8bf*)&B[(wn + nt*16 + lc) * 64 + ((((kk>>3) + lq) ^ (lc & 7)) * 8)];
#pragma unroll
            for (int mt = 0; mt < 4; mt++)
#pragma unroll
                for (int nt = 0; nt < 4; nt++)
                    acc[mt][nt] = __builtin_amdgcn_mfma_f32_16x16x32_bf16(af[mt], bf[nt], acc[mt][nt], 0, 0, 0);
        }
    };

    STAGE(As0, Bs0, 0);
#pragma unroll
    for (int it = 0; it < 6; ++it) {
        const int k0 = it * 128;
        if (k0 + 64 < C_) {
            STAGE(As1, Bs1, k0 + 64);
            asm volatile("s_waitcnt vmcnt(8)" ::: "memory");
        } else {
            asm volatile("s_waitcnt vmcnt(0)" ::: "memory");
        }
        SBAR();
        COMPUTE(As0, Bs0);
        SBAR();
        if (k0 + 128 < C_) {
            STAGE(As0, Bs0, k0 + 128);
            asm volatile("s_waitcnt vmcnt(8)" ::: "memory");
        } else {
            asm volatile("s_waitcnt vmcnt(0)" ::: "memory");
        }
        SBAR();
        COMPUTE(As1, Bs1);
        if (it < 5) SBAR();
    }

#pragma unroll
    for (int mt = 0; mt < 4; mt++) {
#pragma unroll
        for (int r = 0; r < 4; r++) {
            int m = m0 + wm + mt*16 + lq*4 + r;
            if (m >= NTOK) continue;
            unsigned um = (unsigned)m;
            int b = um / (unsigned)N_, n = um % (unsigned)N_;
#pragma unroll
            for (int nt = 0; nt < 4; nt++) {
                int c = c0 + wn + nt*16 + lc;
                int comp = c / C_, rem = c % C_;
                int h = rem >> 6, d0 = rem & 63;
                float val = acc[mt][nt][r] * ((comp == 0) ? SCALE : 1.0f);
                if (comp == 2) {
                    vt[((size_t)((b*H_ + h)*HD_ + d0))*NPADV + n] = f2bf(val);
                } else {
                    ushort_t* dst = (comp == 0) ? qb : kb;
                    dst[((size_t)((b*H_ + h)*N_ + n))*HD_ + d0] = f2bf(val);
                }
            }
        }
    }
}

// ---------------- attention: swapped QK^T + K-slot permutation => P stays in registers ----------------
// K row j stored at LDS slot sigma(j): j=32d+8a+4b+c -> slot=32d+16b+4a+c (bijection).
// Linear frag reads (t4*16+lc) then yield acc[t4][r] = S[i=myrow][j=32(t4>>1)+4(t4&1)+8lq+r],
// so {acc0,acc1} packs straight into PV A-frag pf0 (j 0..31) and {acc2,acc3} into pf1 —
// NO P LDS round-trip. rpe prologue aliases onto Ks; Ps eliminated (LDS 30K->21K).
#define LDT  72
#define LUTS 9

__global__ __launch_bounds__(256) void attn_kernel(
        const ushort_t* __restrict__ qb, const ushort_t* __restrict__ kb,
        const ushort_t* __restrict__ vt, const float* __restrict__ rpe,
        const unsigned char* __restrict__ bucketT, ushort_t* __restrict__ ao) {
    __shared__ __align__(16) ushort_t Ks[64*LDT];   // prologue alias rows 0..15: rpe^T
    __shared__ __align__(16) ushort_t Vs[64*LDT];   // prologue alias: Q tile; loop: V^T Vs[d][j]
    __shared__ float lut[64*LUTS];                  // col 8: lsum broadcast (epilogue)

    const int bh = blockIdx.x, it = blockIdx.y;     // bh-major: all i-tiles of bh on one XCD
    const int b  = bh / H_, hh = bh % H_;
    const int i0 = it * 64;
    const int t  = threadIdx.x;
    const int w  = t >> 6, lane = t & 63, lc = lane & 15, lq = lane >> 4;
    const int row_w = w * 16;                       // wave strip (16 rows)

    const ushort_t* qp = qb + (size_t)bh * N_ * HD_;
    const ushort_t* kp = kb + (size_t)bh * N_ * HD_;
    const ushort_t* vp = vt + (size_t)bh * HD_ * NPADV;

    // ---- stage Q into Vs (zero rows >= N) ----
    {
        int row = t >> 2, d0 = (t & 3) * 16;
        int gi = i0 + row;
        u8s h0 = (u8s)0, h1 = (u8s)0;
        if (gi < N_) {
            h0 = *(const u8s*)(qp + (size_t)gi * HD_ + d0);
            h1 = *(const u8s*)(qp + (size_t)gi * HD_ + d0 + 8);
        }
        *(u8s*)&Vs[row*LDT + d0]     = h0;
        *(u8s*)&Vs[row*LDT + d0 + 8] = h1;
    }
    // ---- stage rpe^T into Ks rows 0..7 (row=m, col=d), zero rows 8..15 ----
    if (t < 64) {
        float4 r0 = *(const float4*)(rpe + t*8);
        float4 r1 = *(const float4*)(rpe + t*8 + 4);
        Ks[0*LDT + t] = f2bf(r0.x); Ks[1*LDT + t] = f2bf(r0.y);
        Ks[2*LDT + t] = f2bf(r0.z); Ks[3*LDT + t] = f2bf(r0.w);
        Ks[4*LDT + t] = f2bf(r1.x); Ks[5*LDT + t] = f2bf(r1.y);
        Ks[6*LDT + t] = f2bf(r1.z); Ks[7*LDT + t] = f2bf(r1.w);
    } else if (t < 128) {
        int idx = t - 64;
        int m = 8 + (idx >> 3), c = (idx & 7) * 8;
        *(u8s*)&Ks[m*LDT + c] = (u8s)0;
    }
    __syncthreads();

    // ---- Q A-fragments (held all K-tiles) ----
    s8bf qf0 = *(s8bf*)&Vs[(row_w + lc)*LDT + lq*8];
    s8bf qf1 = *(s8bf*)&Vs[(row_w + lc)*LDT + 32 + lq*8];

    // ---- lut = Q @ rpe via MFMA (wave-private rows; rf reads precede loop's first barrier) ----
    {
        s8bf rf0 = *(s8bf*)&Ks[lc*LDT + lq*8];
        s8bf rf1 = *(s8bf*)&Ks[lc*LDT + 32 + lq*8];
        v4f la = (v4f){0.f, 0.f, 0.f, 0.f};
        la = __builtin_amdgcn_mfma_f32_16x16x32_bf16(qf0, rf0, la, 0, 0, 0);
        la = __builtin_amdgcn_mfma_f32_16x16x32_bf16(qf1, rf1, la, 0, 0, 0);
        if (lc < 8) {
#pragma unroll
            for (int r = 0; r < 4; r++)
                lut[(row_w + lq*4 + r)*LUTS + lc] = la[r];
        }
    }

    // ---- prologue prefetch: K/V tile 0 + bucket tile 0 (i-row of symmetric table) ----
    const int srow = t >> 2, sd0 = (t & 3) * 16;
    // K staging slot: sigma(srow) — j=32d+8a+4b+c -> slot=32d+16b+4a+c
    const int kslot = ((srow >> 5) * 2 + ((srow >> 2) & 1)) * 16 + ((srow >> 3) & 3) * 4 + (srow & 3);
    u8s krg0, krg1, vrg0, vrg1;
    {
        const ushort_t* ks = kp + (size_t)srow * HD_ + sd0;
        krg0 = *(const u8s*)ks; krg1 = *(const u8s*)(ks + 8);
        const ushort_t* vs = vp + (size_t)srow * NPADV + sd0;
        vrg0 = *(const u8s*)vs; vrg1 = *(const u8s*)(vs + 8);
    }
    int myrow = i0 + row_w + lc; if (myrow > N_ - 1) myrow = N_ - 1;   // lane's Q-row (clamped)
    const unsigned char* bkrow = bucketT + (size_t)myrow * NPAD;
    const int lutbase = (row_w + lc) * LUTS;
    // per-lane j base within tile for quadrant t4: 32*(t4>>1) + 4*(t4&1) + 8*lq
    const int jb0 = 8*lq, jb1 = 8*lq + 4, jb2 = 8*lq + 32, jb3 = 8*lq + 36;
    unsigned bk4[4];
    bk4[0] = *(const unsigned*)(bkrow + jb0);
    bk4[1] = *(const unsigned*)(bkrow + jb1);
    bk4[2] = *(const unsigned*)(bkrow + jb2);
    bk4[3] = *(const unsigned*)(bkrow + jb3);

    v4f o[4];
    float lsum = 0.f;
#pragma unroll
    for (int dt = 0; dt < 4; dt++) o[dt] = (v4f){0.f, 0.f, 0.f, 0.f};

    for (int jt = 0; jt < 17; jt++) {
        const int j0 = jt * 64;
        __syncthreads();   // prev tile's frag reads (and prologue qf/rf) done
        {
            ushort_t* kd = &Ks[kslot*LDT + sd0];
            *(u8s*)kd = krg0; *(u8s*)(kd + 8) = krg1;
            ushort_t* vd = &Vs[srow*LDT + sd0];
            *(u8s*)vd = vrg0; *(u8s*)(vd + 8) = vrg1;
        }
        __syncthreads();   // staging visible

        // prefetch next tile's K/V + buckets (hidden behind this tile's compute)
        unsigned bk4n[4];
        if (jt < 16) {
            int gj = j0 + 64 + srow; if (gj > N_ - 1) gj = N_ - 1;
            const ushort_t* ks = kp + (size_t)gj * HD_ + sd0;
            krg0 = *(const u8s*)ks; krg1 = *(const u8s*)(ks + 8);
            const ushort_t* vs = vp + (size_t)srow * NPADV + (j0 + 64) + sd0;
            vrg0 = *(const u8s*)vs; vrg1 = *(const u8s*)(vs + 8);
            bk4n[0] = *(const unsigned*)(bkrow + j0 + 64 + jb0);
            bk4n[1] = *(const unsigned*)(bkrow + j0 + 64 + jb1);
            bk4n[2] = *(const unsigned*)(bkrow + j0 + 64 + jb2);
            bk4n[3] = *(const unsigned*)(bkrow + j0 + 64 + jb3);
        }

        // ---- S^T = K Q^T (swapped, slot-permuted): acc[t4][r] = S[myrow][j0 + jb{t4} + r] ----
        v4f acc[4];
#pragma unroll
        for (int t4 = 0; t4 < 4; t4++) acc[t4] = (v4f){0.f, 0.f, 0.f, 0.f};
#pragma unroll
        for (int t4 = 0; t4 < 4; t4++) {
            s8bf kf0 = *(s8bf*)&Ks[(t4*16 + lc)*LDT + lq*8];
            s8bf kf1 = *(s8bf*)&Ks[(t4*16 + lc)*LDT + 32 + lq*8];
            acc[t4] = __builtin_amdgcn_mfma_f32_16x16x32_bf16(kf0, qf0, acc[t4], 0, 0, 0);
            acc[t4] = __builtin_amdgcn_mfma_f32_16x16x32_bf16(kf1, qf1, acc[t4], 0, 0, 0);
        }

        // ---- bias + exp (no max; logits provably small), per-lane row-local ----
        float pp[4][4];
        const int jbs[4] = {jb0, jb1, jb2, jb3};
#pragma unroll
        for (int t4 = 0; t4 < 4; t4++) {
#pragma unroll
            for (int r = 0; r < 4; r++) {
                int bk = (bk4[t4] >> (8*r)) & 0xFF;
                float sv = acc[t4][r] + lut[lutbase + bk];
                float p = __expf(sv);
                if (jt == 16 && (jbs[t4] + r) > 0) p = 0.f;   // tail: only j==1024 valid
                lsum += p;
                pp[t4][r] = p;
            }
        }
#pragma unroll
        for (int t4 = 0; t4 < 4; t4++) bk4[t4] = bk4n[t4];

        // ---- pack P directly into PV A-frags (registers only; no LDS) ----
        __align__(16) ushort_t ph[16] = {
            f2bf(pp[0][0]), f2bf(pp[0][1]), f2bf(pp[0][2]), f2bf(pp[0][3]),
            f2bf(pp[1][0]), f2bf(pp[1][1]), f2bf(pp[1][2]), f2bf(pp[1][3]),
            f2bf(pp[2][0]), f2bf(pp[2][1]), f2bf(pp[2][2]), f2bf(pp[2][3]),
            f2bf(pp[3][0]), f2bf(pp[3][1]), f2bf(pp[3][2]), f2bf(pp[3][3])};
        s8bf pf0 = *(s8bf*)&ph[0];
        s8bf pf1 = *(s8bf*)&ph[8];

        // ---- O += P V ----
#pragma unroll
        for (int dt = 0; dt < 4; dt++) {
            s8bf vf0 = *(s8bf*)&Vs[(dt*16 + lc)*LDT + lq*8];
            s8bf vf1 = *(s8bf*)&Vs[(dt*16 + lc)*LDT + 32 + lq*8];
            o[dt] = __builtin_amdgcn_mfma_f32_16x16x32_bf16(pf0, vf0, o[dt], 0, 0, 0);
            o[dt] = __builtin_amdgcn_mfma_f32_16x16x32_bf16(pf1, vf1, o[dt], 0, 0, 0);
        }
    }

    // ---- epilogue: lsum partial over this lane's j-subset; reduce over lq, bcast via lut col 8 ----
    lsum += __shfl_xor(lsum, 16);
    lsum += __shfl_xor(lsum, 32);          // lanes {lc,lc+16,lc+32,lc+48} hold total sum(row)
    if (lq == 0) lut[(row_w + lc)*LUTS + 8] = lsum;
    __builtin_amdgcn_s_waitcnt(0);          // lgkm drain before same-wave read (cheap, wave-private rows)
#pragma unroll
    for (int r = 0; r < 4; r++) {
        int i = i0 + row_w + lq*4 + r;
        if (i < N_) {
            float inv = 1.0f / lut[(row_w + lq*4 + r)*LUTS + 8];
#pragma unroll
            for (int dt = 0; dt < 4; dt++)
                ao[((size_t)(b*N_ + i))*C_ + hh*HD_ + dt*16 + lc] = f2bf(o[dt][r] * inv);
        }
    }
}

// ---------------- proj: out(8200x768) = aob @ wprojb^T + bias, f32 out ----------------
// same T3+T4 pipeline + T1 bijective XCD swizzle (nwg=390: q=48, r=6)
__global__ __launch_bounds__(256) void proj_kernel(
        const ushort_t* __restrict__ ab, const ushort_t* __restrict__ wb,
        const float* __restrict__ bias, float* __restrict__ out) {
    __shared__ __align__(16) ushort_t As0[128*64];
    __shared__ __align__(16) ushort_t Bs0[128*64];
    __shared__ __align__(16) ushort_t As1[128*64];
    __shared__ __align__(16) ushort_t Bs1[128*64];
    const int L = blockIdx.x + blockIdx.y * 65;
    const int xcd = L & 7, idx = L >> 3;
    const int wg = (xcd < 6 ? xcd * 49 : 6 * 49 + (xcd - 6) * 48) + idx;
    const int m0 = (wg / 6) * 128, c0 = (wg % 6) * 128;
    const int t = threadIdx.x;
    const int w = t >> 6, lane = t & 63, lc = lane & 15, lq = lane >> 4;
    const int wm = (w >> 1) * 64, wn = (w & 1) * 64;
    const int srow8 = w * 32 + (lane >> 3);
    const int gsw8  = (((lane & 7) ^ (lane >> 3)) & 7) * 8;

    v4f acc[4][4];
#pragma unroll
    for (int mt = 0; mt < 4; mt++)
#pragma unroll
        for (int nt = 0; nt < 4; nt++) acc[mt][nt] = (v4f){0.f, 0.f, 0.f, 0.f};

    auto STAGE = [&](ushort_t* Ad, ushort_t* Bd, int k0) {
#pragma unroll
        for (int i = 0; i < 4; i++) {
            int row = srow8 + i * 8;
            int m = m0 + row; if (m > NTOK - 1) m = NTOK - 1;
            GLOAD16(ab + (size_t)m * C_ + k0 + gsw8,           &Ad[(w*32 + i*8) * 64]);
            GLOAD16(wb + (size_t)(c0 + row) * C_ + k0 + gsw8,  &Bd[(w*32 + i*8) * 64]);
        }
    };
    auto COMPUTE = [&](const ushort_t* A, const ushort_t* B) {
#pragma unroll
        for (int kk = 0; kk < 64; kk += 32) {
            s8bf af[4], bf[4];
#pragma unroll
            for (int mt = 0; mt < 4; mt++)
                af[mt] = *(const s8bf*)&A[(wm + mt*16 + lc) * 64 + ((((kk>>3) + lq) ^ (lc & 7)) * 8)];
#pragma unroll
            for (int nt = 0; nt < 4; nt++)
                bf[nt] = *(const s8bf*)&B[(wn + nt*16 + lc) * 64 + ((((kk>>3) + lq) ^ (lc & 7)) * 8)];
#pragma unroll
            for (int mt = 0; mt < 4; mt++)
#pragma unroll
                for (int nt = 0; nt < 4; nt++)
                    acc[mt][nt] = __builtin_amdgcn_mfma_f32_16x16x32_bf16(af[mt], bf[nt], acc[mt][nt], 0, 0, 0);
        }
    };

    STAGE(As0, Bs0, 0);
#pragma unroll
    for (int it = 0; it < 6; ++it) {
        const int k0 = it * 128;
        if (k0 + 64 < C_) {
            STAGE(As1, Bs1, k0 + 64);
            asm volatile("s_waitcnt vmcnt(8)" ::: "memory");
        } else {
            asm volatile("s_waitcnt vmcnt(0)" ::: "memory");
        }
        SBAR();
        COMPUTE(As0, Bs0);
        SBAR();
        if (k0 + 128 < C_) {
            STAGE(As0, Bs0, k0 + 128);
            asm volatile("s_waitcnt vmcnt(8)" ::: "memory");
        } else {
            asm volatile("s_waitcnt vmcnt(0)" ::: "memory");
        }
        SBAR();
        COMPUTE(As1, Bs1);
        if (it < 5) SBAR();
    }

    float pb[4];
#pragma unroll
    for (int nt = 0; nt < 4; nt++) pb[nt] = bias[c0 + wn + nt*16 + lc];
#pragma unroll
    for (int mt = 0; mt < 4; mt++) {
#pragma unroll
        for (int r = 0; r < 4; r++) {
            int m = m0 + wm + mt*16 + lq*4 + r;
            if (m >= NTOK) continue;
#pragma unroll
            for (int nt = 0; nt < 4; nt++) {
                int c = c0 + wn + nt*16 + lc;
                out[(size_t)m * C_ + c] = acc[mt][nt][r] + pb[nt];
            }
        }
    }
}

extern "C" void kernel_launch(void* const* d_in, const int* in_sizes, int n_in,
                              void* d_out, int out_size, void* d_ws, size_t ws_size,
                              hipStream_t stream) {
    const float* x      = (const float*)d_in[0];
    const float* qkv_w  = (const float*)d_in[1];
    const float* proj_w = (const float*)d_in[2];
    const float* proj_b = (const float*)d_in[3];
    const float* rpe_w  = (const float*)d_in[4];
    float* out = (float*)d_out;

    char* ws = (char*)d_ws;
    ushort_t* xb   = (ushort_t*)(ws + XB_OFF_B);
    ushort_t* wqkv = (ushort_t*)(ws + WQKV_OFF_B);
    ushort_t* wprj = (ushort_t*)(ws + WPROJ_OFF_B);
    ushort_t* qb   = (ushort_t*)(ws + QB_OFF_B);
    ushort_t* kb   = (ushort_t*)(ws + KB_OFF_B);
    ushort_t* aob  = (ushort_t*)(ws + AOB_OFF_B);
    ushort_t* vt   = (ushort_t*)(ws + VT_OFF_B);
    unsigned char* bucketT = (unsigned char*)(ws + BUCKET_OFF_B);

    const int ncast = (NTOK*C_ + 3*C_*C_ + C_*C_) / 8;
    bucket_kernel<<<dim3((N_*NPAD + 255)/256), 256, 0, stream>>>(bucketT);
    cast_kernel<<<dim3((ncast + 255)/256), 256, 0, stream>>>(x, qkv_w, proj_w, xb, wqkv, wprj);
    qkv_kernel<<<dim3(65, 18), 256, 0, stream>>>(xb, wqkv, qb, kb, vt);
    attn_kernel<<<dim3(96, 17), 256, 0, stream>>>(qb, kb, vt, rpe_w, bucketT, aob);
    proj_kernel<<<dim3(65, 6), 256, 0, stream>>>(aob, wprj, proj_b, out);
}

// Round 9
// 225.496 us; speedup vs baseline: 1.1505x; 1.0250x over previous
//
#include <hip/hip_runtime.h>
#include <math.h>

#define B_    8
#define N_    1025
#define H_    12
#define HD_   64
#define C_    768
#define BH_   (B_*H_)
#define NTOK  (B_*N_)          // 8200
#define SCALE 0.125f
#define NPAD  1092             // bucketT row stride (mult of 4); table is SYMMETRIC: [a][b]=bucket(a,b)
#define NPADV 1088             // vt row stride (17*64)

#define QKV_ELEMS (BH_*N_*HD_)         // 6,297,600

// ws layout (bytes)
#define XB_OFF_B     ((size_t)0)
#define WQKV_OFF_B   (XB_OFF_B + (size_t)NTOK*C_*2)
#define WPROJ_OFF_B  (WQKV_OFF_B + (size_t)3*C_*C_*2)
#define QB_OFF_B     (WPROJ_OFF_B + (size_t)C_*C_*2)
#define KB_OFF_B     (QB_OFF_B + (size_t)QKV_ELEMS*2)
#define AOB_OFF_B    (KB_OFF_B + (size_t)QKV_ELEMS*2)
#define VT_OFF_B     (AOB_OFF_B + (size_t)QKV_ELEMS*2)
#define BUCKET_OFF_B (VT_OFF_B + (size_t)BH_*HD_*NPADV*2)

typedef __attribute__((ext_vector_type(8))) short s8bf;
typedef __attribute__((ext_vector_type(8))) unsigned short u8s;
typedef __attribute__((ext_vector_type(4))) float v4f;
typedef unsigned short ushort_t;

// async global -> LDS, 16B per lane. LDS dest must be wave-uniform base
// (HW writes base + lane*16); global src is per-lane.
#define GLOAD16(gp, lp) __builtin_amdgcn_global_load_lds( \
    (const __attribute__((address_space(1))) unsigned int*)(gp), \
    (__attribute__((address_space(3))) unsigned int*)(lp), 16, 0, 0)

// raw workgroup barrier with compiler memory fence (no vmcnt drain, unlike __syncthreads)
#define SBAR() do { \
    __builtin_amdgcn_sched_barrier(0); \
    asm volatile("s_barrier" ::: "memory"); \
    __builtin_amdgcn_sched_barrier(0); \
} while (0)

// hand-RNE f32->bf16 (KEEP for all persistent tensors: v_cvt_pk_bf16_f32 asm path
// failed absmax in R3 — rounding-mode bias accumulated coherently)
__device__ __forceinline__ unsigned short f2bf(float x) {
    union { float f; unsigned u; } v; v.f = x;
    unsigned r = v.u + 0x7FFFu + ((v.u >> 16) & 1u);
    return (unsigned short)(r >> 16);
}
// round-half-up pack of two NONNEGATIVE floats (P values): differs from RNE only on
// exact ties (measure-zero after exp; no coherent bias). 5 ops/pair vs ~11.
__device__ __forceinline__ unsigned packbf_hu(float lo, float hi) {
    union { float f; unsigned u; } a, b; a.f = lo; b.f = hi;
    return ((a.u + 0x8000u) >> 16) | ((b.u + 0x8000u) & 0xFFFF0000u);
}

// ---- bucketT[a][b] = bucket(a,b), integer-exact & SYMMETRIC: {d2=0:0, d2<=2:1, d2<=12:2, else 3}, cls:7 ----
__global__ void bucket_kernel(unsigned char* __restrict__ bucketT) {
    int tid = blockIdx.x * 256 + threadIdx.x;
    if (tid >= N_ * NPAD) return;
    unsigned ut = (unsigned)tid;
    int j = ut / (unsigned)NPAD, i = ut % (unsigned)NPAD;
    if (i >= N_) i = N_ - 1;
    int bk;
    if (i < 1 || j < 1) {
        bk = 7;
    } else {
        int pi = i - 1, pj = j - 1;
        int dy = (pi >> 5) - (pj >> 5);
        int dx = (pi & 31) - (pj & 31);
        int d2 = dy*dy + dx*dx;
        bk = (d2 == 0) ? 0 : ((d2 <= 2) ? 1 : ((d2 <= 12) ? 2 : 3));
    }
    bucketT[tid] = (unsigned char)bk;
}

// ---------------- fused f32 -> bf16 cast (x, qkv_w, proj_w) ----------------
__global__ __launch_bounds__(256) void cast_kernel(
        const float* __restrict__ x, const float* __restrict__ w1,
        const float* __restrict__ w2,
        ushort_t* __restrict__ xb, ushort_t* __restrict__ w1b,
        ushort_t* __restrict__ w2b) {
    const int NX = NTOK * C_ / 8, NW1 = 3 * C_ * C_ / 8, NW2 = C_ * C_ / 8;
    int g = blockIdx.x * 256 + threadIdx.x;
    const float* src; ushort_t* dst; int idx;
    if (g < NX)                 { src = x;  dst = xb;  idx = g; }
    else if (g < NX + NW1)      { src = w1; dst = w1b; idx = g - NX; }
    else if (g < NX + NW1 + NW2){ src = w2; dst = w2b; idx = g - NX - NW1; }
    else return;
    size_t off = (size_t)idx * 8;
    float4 a = *(const float4*)(src + off);
    float4 c = *(const float4*)(src + off + 4);
    __align__(16) ushort_t h[8] = {f2bf(a.x), f2bf(a.y), f2bf(a.z), f2bf(a.w),
                                   f2bf(c.x), f2bf(c.y), f2bf(c.z), f2bf(c.w)};
    *(u8s*)(dst + off) = *(u8s*)h;
}

// ---------------- bf16 MFMA GEMM: 128x128 tile, BK=64, DOUBLE-BUFFERED global_load_lds ----------------
// T1 XCD swizzle (bijective, m204): xcd=L%8 owns contiguous wg-range, c0-fastest.
__global__ __launch_bounds__(256) void qkv_kernel(
        const ushort_t* __restrict__ xb, const ushort_t* __restrict__ wb,
        ushort_t* __restrict__ qb, ushort_t* __restrict__ kb, ushort_t* __restrict__ vt) {
    __shared__ __align__(16) ushort_t As0[128*64];
    __shared__ __align__(16) ushort_t Bs0[128*64];
    __shared__ __align__(16) ushort_t As1[128*64];
    __shared__ __align__(16) ushort_t Bs1[128*64];
    // bijective XCD remap: nwg=1170, q=146, r=2
    const int L = blockIdx.x + blockIdx.y * 65;
    const int xcd = L & 7, idx = L >> 3;
    const int wg = (xcd < 2 ? xcd * 147 : 2 * 147 + (xcd - 2) * 146) + idx;
    const int m0 = (wg / 18) * 128, c0 = (wg % 18) * 128;
    const int t = threadIdx.x;
    const int w = t >> 6, lane = t & 63, lc = lane & 15, lq = lane >> 4;
    const int wm = (w >> 1) * 64, wn = (w & 1) * 64;
    const int srow8 = w * 32 + (lane >> 3);                    // + i*8 = row within tile
    const int gsw8  = (((lane & 7) ^ (lane >> 3)) & 7) * 8;    // swizzled source col (ushorts)

    v4f acc[4][4];
#pragma unroll
    for (int mt = 0; mt < 4; mt++)
#pragma unroll
        for (int nt = 0; nt < 4; nt++) acc[mt][nt] = (v4f){0.f, 0.f, 0.f, 0.f};

    auto STAGE = [&](ushort_t* Ad, ushort_t* Bd, int k0) {
#pragma unroll
        for (int i = 0; i < 4; i++) {
            int row = srow8 + i * 8;
            int m = m0 + row; if (m > NTOK - 1) m = NTOK - 1;   // clamp: dup reads, rows masked in epilogue
            GLOAD16(xb + (size_t)m * C_ + k0 + gsw8,           &Ad[(w*32 + i*8) * 64]);
            GLOAD16(wb + (size_t)(c0 + row) * C_ + k0 + gsw8,  &Bd[(w*32 + i*8) * 64]);
        }
    };
    auto COMPUTE = [&](const ushort_t* A, const ushort_t* B) {
#pragma unroll
        for (int kk = 0; kk < 64; kk += 32) {
            s8bf af[4], bf[4];
#pragma unroll
            for (int mt = 0; mt < 4; mt++)
                af[mt] = *(const s8bf*)&A[(wm + mt*16 + lc) * 64 + ((((kk>>3) + lq) ^ (lc & 7)) * 8)];
#pragma unroll
            for (int nt = 0; nt < 4; nt++)
                bf[nt] = *(const s8bf*)&B[(wn + nt*16 + lc) * 64 + ((((kk>>3) + lq) ^ (lc & 7)) * 8)];
#pragma unroll
            for (int mt = 0; mt < 4; mt++)
#pragma unroll
                for (int nt = 0; nt < 4; nt++)
                    acc[mt][nt] = __builtin_amdgcn_mfma_f32_16x16x32_bf16(af[mt], bf[nt], acc[mt][nt], 0, 0, 0);
        }
    };

    STAGE(As0, Bs0, 0);
#pragma unroll
    for (int it = 0; it < 6; ++it) {
        const int k0 = it * 128;
        if (k0 + 64 < C_) {
            STAGE(As1, Bs1, k0 + 64);
            asm volatile("s_waitcnt vmcnt(8)" ::: "memory");
        } else {
            asm volatile("s_waitcnt vmcnt(0)" ::: "memory");
        }
        SBAR();
        COMPUTE(As0, Bs0);
        SBAR();
        if (k0 + 128 < C_) {
            STAGE(As0, Bs0, k0 + 128);
            asm volatile("s_waitcnt vmcnt(8)" ::: "memory");
        } else {
            asm volatile("s_waitcnt vmcnt(0)" ::: "memory");
        }
        SBAR();
        COMPUTE(As1, Bs1);
        if (it < 5) SBAR();
    }

#pragma unroll
    for (int mt = 0; mt < 4; mt++) {
#pragma unroll
        for (int r = 0; r < 4; r++) {
            int m = m0 + wm + mt*16 + lq*4 + r;
            if (m >= NTOK) continue;
            unsigned um = (unsigned)m;
            int b = um / (unsigned)N_, n = um % (unsigned)N_;
#pragma unroll
            for (int nt = 0; nt < 4; nt++) {
                int c = c0 + wn + nt*16 + lc;
                int comp = c / C_, rem = c % C_;
                int h = rem >> 6, d0 = rem & 63;
                float val = acc[mt][nt][r] * ((comp == 0) ? SCALE : 1.0f);
                if (comp == 2) {
                    vt[((size_t)((b*H_ + h)*HD_ + d0))*NPADV + n] = f2bf(val);
                } else {
                    ushort_t* dst = (comp == 0) ? qb : kb;
                    dst[((size_t)((b*H_ + h)*N_ + n))*HD_ + d0] = f2bf(val);
                }
            }
        }
    }
}

// ---------------- attention: swapped QK^T + K-slot perm (P in regs) + [64][64] XOR-swizzled LDS ----------------
// LDS [row][64] with address swizzle granule' = g ^ (row&7) on BOTH write and read
// (reg-staged, so plain addr swizzle is legal). Frag reads hit the b128 bank floor.
// Main loop peeled: tiles 0..15 mask-free; tile 16 handled separately.
// P pack: round-half-up pair pack (ties-only deviation from RNE; P>=0 so no carry hazard).
#define LUTS 9

__global__ __launch_bounds__(256) void attn_kernel(
        const ushort_t* __restrict__ qb, const ushort_t* __restrict__ kb,
        const ushort_t* __restrict__ vt, const float* __restrict__ rpe,
        const unsigned char* __restrict__ bucketT, ushort_t* __restrict__ ao) {
    __shared__ __align__(16) ushort_t Ks[64*64];    // prologue alias rows 0..15: rpe^T
    __shared__ __align__(16) ushort_t Vs[64*64];    // prologue alias: Q tile; loop: V^T Vs[d][j]
    __shared__ float lut[64*LUTS];                  // col 8: lsum broadcast (epilogue)

    const int bh = blockIdx.x, it = blockIdx.y;     // bh-major: all i-tiles of bh on one XCD
    const int b  = bh / H_, hh = bh % H_;
    const int i0 = it * 64;
    const int t  = threadIdx.x;
    const int w  = t >> 6, lane = t & 63, lc = lane & 15, lq = lane >> 4;
    const int row_w = w * 16;                       // wave strip (16 rows)
    const int rs = lc & 7;                          // read-swizzle key (all frag rows ≡ lc mod 8)
    const int gA = ((lq ^ rs) & 7) * 8;             // frag0 swizzled col (granule lq)
    const int gB = (((lq + 4) ^ rs) & 7) * 8;       // frag1 swizzled col (granule 4+lq)

    const ushort_t* qp = qb + (size_t)bh * N_ * HD_;
    const ushort_t* kp = kb + (size_t)bh * N_ * HD_;
    const ushort_t* vp = vt + (size_t)bh * HD_ * NPADV;

    // ---- stage Q into Vs (zero rows >= N), addr-swizzled ----
    {
        int row = t >> 2, g0 = (t & 3) * 2, qrs = row & 7;
        int gi = i0 + row;
        u8s h0 = (u8s)0, h1 = (u8s)0;
        if (gi < N_) {
            h0 = *(const u8s*)(qp + (size_t)gi * HD_ + g0*8);
            h1 = *(const u8s*)(qp + (size_t)gi * HD_ + g0*8 + 8);
        }
        *(u8s*)&Vs[row*64 + ((g0 ^ qrs) * 8)]       = h0;
        *(u8s*)&Vs[row*64 + (((g0+1) ^ qrs) * 8)]   = h1;
    }
    // ---- stage rpe^T into Ks rows 0..7 (row=m, col=d), zero rows 8..15, addr-swizzled ----
    if (t < 64) {
        float4 r0 = *(const float4*)(rpe + t*8);
        float4 r1 = *(const float4*)(rpe + t*8 + 4);
        const int gr = t >> 3, go = t & 7;
        float vals[8] = {r0.x, r0.y, r0.z, r0.w, r1.x, r1.y, r1.z, r1.w};
#pragma unroll
        for (int m = 0; m < 8; m++)
            Ks[m*64 + ((gr ^ (m & 7)) * 8) + go] = f2bf(vals[m]);
    } else if (t < 128) {
        int idx = t - 64;
        int m = 8 + (idx >> 3), g = idx & 7;
        *(u8s*)&Ks[m*64 + ((g ^ (m & 7)) * 8)] = (u8s)0;
    }
    __syncthreads();

    // ---- Q A-fragments (held all K-tiles) ----
    s8bf qf0 = *(s8bf*)&Vs[(row_w + lc)*64 + gA];
    s8bf qf1 = *(s8bf*)&Vs[(row_w + lc)*64 + gB];

    // ---- lut = Q @ rpe via MFMA (wave-private rows; rf reads precede loop's first barrier) ----
    {
        s8bf rf0 = *(s8bf*)&Ks[lc*64 + gA];
        s8bf rf1 = *(s8bf*)&Ks[lc*64 + gB];
        v4f la = (v4f){0.f, 0.f, 0.f, 0.f};
        la = __builtin_amdgcn_mfma_f32_16x16x32_bf16(qf0, rf0, la, 0, 0, 0);
        la = __builtin_amdgcn_mfma_f32_16x16x32_bf16(qf1, rf1, la, 0, 0, 0);
        if (lc < 8) {
#pragma unroll
            for (int r = 0; r < 4; r++)
                lut[(row_w + lq*4 + r)*LUTS + lc] = la[r];
        }
    }

    // ---- prologue prefetch: K/V tile 0 + bucket tile 0 (i-row of symmetric table) ----
    const int srow = t >> 2, g0 = (t & 3) * 2, sd0 = g0 * 8;
    // K staging slot: sigma(srow) — j=32d+8a+4b+c -> slot=32d+16b+4a+c
    const int kslot = ((srow >> 5) * 2 + ((srow >> 2) & 1)) * 16 + ((srow >> 3) & 3) * 4 + (srow & 3);
    const int krs = kslot & 7, vrs = srow & 7;
    ushort_t* const kd0 = &Ks[kslot*64 + ((g0 ^ krs) * 8)];
    ushort_t* const kd1 = &Ks[kslot*64 + (((g0+1) ^ krs) * 8)];
    ushort_t* const vd0 = &Vs[srow*64 + ((g0 ^ vrs) * 8)];
    ushort_t* const vd1 = &Vs[srow*64 + (((g0+1) ^ vrs) * 8)];
    u8s krg0, krg1, vrg0, vrg1;
    {
        const ushort_t* ks = kp + (size_t)srow * HD_ + sd0;
        krg0 = *(const u8s*)ks; krg1 = *(const u8s*)(ks + 8);
        const ushort_t* vs = vp + (size_t)srow * NPADV + sd0;
        vrg0 = *(const u8s*)vs; vrg1 = *(const u8s*)(vs + 8);
    }
    int myrow = i0 + row_w + lc; if (myrow > N_ - 1) myrow = N_ - 1;   // lane's Q-row (clamped)
    const unsigned char* bkrow = bucketT + (size_t)myrow * NPAD;
    const int lutbase = (row_w + lc) * LUTS;
    // per-lane j base within tile for quadrant t4: 32*(t4>>1) + 4*(t4&1) + 8*lq
    const int jb0 = 8*lq, jb1 = 8*lq + 4, jb2 = 8*lq + 32, jb3 = 8*lq + 36;
    unsigned bk4[4];
    bk4[0] = *(const unsigned*)(bkrow + jb0);
    bk4[1] = *(const unsigned*)(bkrow + jb1);
    bk4[2] = *(const unsigned*)(bkrow + jb2);
    bk4[3] = *(const unsigned*)(bkrow + jb3);

    v4f o[4];
    float lsum = 0.f;
#pragma unroll
    for (int dt = 0; dt < 4; dt++) o[dt] = (v4f){0.f, 0.f, 0.f, 0.f};

    // ================= main loop: tiles 0..15, mask-free =================
    for (int jt = 0; jt < 16; jt++) {
        const int j0 = jt * 64;
        __syncthreads();   // prev tile's frag reads (and prologue qf/rf) done
        {
            *(u8s*)kd0 = krg0; *(u8s*)kd1 = krg1;
            *(u8s*)vd0 = vrg0; *(u8s*)vd1 = vrg1;
        }
        __syncthreads();   // staging visible

        // prefetch next tile (jt+1 <= 16; row clamps handle the edge)
        unsigned bk4n[4];
        {
            int gj = j0 + 64 + srow; if (gj > N_ - 1) gj = N_ - 1;
            const ushort_t* ks = kp + (size_t)gj * HD_ + sd0;
            krg0 = *(const u8s*)ks; krg1 = *(const u8s*)(ks + 8);
            const ushort_t* vs = vp + (size_t)srow * NPADV + (j0 + 64) + sd0;
            vrg0 = *(const u8s*)vs; vrg1 = *(const u8s*)(vs + 8);
            bk4n[0] = *(const unsigned*)(bkrow + j0 + 64 + jb0);
            bk4n[1] = *(const unsigned*)(bkrow + j0 + 64 + jb1);
            bk4n[2] = *(const unsigned*)(bkrow + j0 + 64 + jb2);
            bk4n[3] = *(const unsigned*)(bkrow + j0 + 64 + jb3);
        }

        // ---- S^T = K Q^T (swapped, slot-permuted) ----
        v4f acc[4];
#pragma unroll
        for (int t4 = 0; t4 < 4; t4++) acc[t4] = (v4f){0.f, 0.f, 0.f, 0.f};
#pragma unroll
        for (int t4 = 0; t4 < 4; t4++) {
            s8bf kf0 = *(s8bf*)&Ks[(t4*16 + lc)*64 + gA];
            s8bf kf1 = *(s8bf*)&Ks[(t4*16 + lc)*64 + gB];
            acc[t4] = __builtin_amdgcn_mfma_f32_16x16x32_bf16(kf0, qf0, acc[t4], 0, 0, 0);
            acc[t4] = __builtin_amdgcn_mfma_f32_16x16x32_bf16(kf1, qf1, acc[t4], 0, 0, 0);
        }

        // ---- bias + exp + half-up pair pack (no mask, no P LDS) ----
        unsigned pw[8];
#pragma unroll
        for (int t4 = 0; t4 < 4; t4++) {
            float p0, p1, p2, p3;
            {
                int k0b = (bk4[t4]      ) & 0xFF; p0 = __expf(acc[t4][0] + lut[lutbase + k0b]);
                int k1b = (bk4[t4] >>  8) & 0xFF; p1 = __expf(acc[t4][1] + lut[lutbase + k1b]);
                int k2b = (bk4[t4] >> 16) & 0xFF; p2 = __expf(acc[t4][2] + lut[lutbase + k2b]);
                int k3b = (bk4[t4] >> 24)       ; p3 = __expf(acc[t4][3] + lut[lutbase + k3b]);
            }
            lsum += (p0 + p1) + (p2 + p3);
            pw[t4*2]     = packbf_hu(p0, p1);
            pw[t4*2 + 1] = packbf_hu(p2, p3);
        }
#pragma unroll
        for (int t4 = 0; t4 < 4; t4++) bk4[t4] = bk4n[t4];
        s8bf pf0 = *(s8bf*)&pw[0];
        s8bf pf1 = *(s8bf*)&pw[4];

        // ---- O += P V ----
#pragma unroll
        for (int dt = 0; dt < 4; dt++) {
            s8bf vf0 = *(s8bf*)&Vs[(dt*16 + lc)*64 + gA];
            s8bf vf1 = *(s8bf*)&Vs[(dt*16 + lc)*64 + gB];
            o[dt] = __builtin_amdgcn_mfma_f32_16x16x32_bf16(pf0, vf0, o[dt], 0, 0, 0);
            o[dt] = __builtin_amdgcn_mfma_f32_16x16x32_bf16(pf1, vf1, o[dt], 0, 0, 0);
        }
    }

    // ================= peeled tile 16 (j0=1024; only j==1024 valid) =================
    {
        __syncthreads();
        {
            *(u8s*)kd0 = krg0; *(u8s*)kd1 = krg1;
            *(u8s*)vd0 = vrg0; *(u8s*)vd1 = vrg1;
        }
        __syncthreads();

        v4f acc[4];
#pragma unroll
        for (int t4 = 0; t4 < 4; t4++) acc[t4] = (v4f){0.f, 0.f, 0.f, 0.f};
#pragma unroll
        for (int t4 = 0; t4 < 4; t4++) {
            s8bf kf0 = *(s8bf*)&Ks[(t4*16 + lc)*64 + gA];
            s8bf kf1 = *(s8bf*)&Ks[(t4*16 + lc)*64 + gB];
            acc[t4] = __builtin_amdgcn_mfma_f32_16x16x32_bf16(kf0, qf0, acc[t4], 0, 0, 0);
            acc[t4] = __builtin_amdgcn_mfma_f32_16x16x32_bf16(kf1, qf1, acc[t4], 0, 0, 0);
        }

        unsigned pw[8];
        const int jbs[4] = {jb0, jb1, jb2, jb3};
#pragma unroll
        for (int t4 = 0; t4 < 4; t4++) {
            float pv[4];
#pragma unroll
            for (int r = 0; r < 4; r++) {
                int bk = (bk4[t4] >> (8*r)) & 0xFF;
                float p = __expf(acc[t4][r] + lut[lutbase + bk]);
                if ((jbs[t4] + r) > 0) p = 0.f;   // only j==1024 valid
                lsum += p;
                pv[r] = p;
            }
            pw[t4*2]     = packbf_hu(pv[0], pv[1]);
            pw[t4*2 + 1] = packbf_hu(pv[2], pv[3]);
        }
        s8bf pf0 = *(s8bf*)&pw[0];
        s8bf pf1 = *(s8bf*)&pw[4];
#pragma unroll
        for (int dt = 0; dt < 4; dt++) {
            s8bf vf0 = *(s8bf*)&Vs[(dt*16 + lc)*64 + gA];
            s8bf vf1 = *(s8bf*)&Vs[(dt*16 + lc)*64 + gB];
            o[dt] = __builtin_amdgcn_mfma_f32_16x16x32_bf16(pf0, vf0, o[dt], 0, 0, 0);
            o[dt] = __builtin_amdgcn_mfma_f32_16x16x32_bf16(pf1, vf1, o[dt], 0, 0, 0);
        }
    }

    // ---- epilogue: lsum partial over this lane's j-subset; reduce over lq, bcast via lut col 8 ----
    lsum += __shfl_xor(lsum, 16);
    lsum += __shfl_xor(lsum, 32);          // lanes {lc,lc+16,lc+32,lc+48} hold total sum(row)
    if (lq == 0) lut[(row_w + lc)*LUTS + 8] = lsum;
    __builtin_amdgcn_s_waitcnt(0);          // lgkm drain before same-wave read (wave-private rows)
#pragma unroll
    for (int r = 0; r < 4; r++) {
        int i = i0 + row_w + lq*4 + r;
        if (i < N_) {
            float inv = 1.0f / lut[(row_w + lq*4 + r)*LUTS + 8];
#pragma unroll
            for (int dt = 0; dt < 4; dt++)
                ao[((size_t)(b*N_ + i))*C_ + hh*HD_ + dt*16 + lc] = f2bf(o[dt][r] * inv);
        }
    }
}

// ---------------- proj: out(8200x768) = aob @ wprojb^T + bias, f32 out ----------------
// same T3+T4 pipeline + T1 bijective XCD swizzle (nwg=390: q=48, r=6)
__global__ __launch_bounds__(256) void proj_kernel(
        const ushort_t* __restrict__ ab, const ushort_t* __restrict__ wb,
        const float* __restrict__ bias, float* __restrict__ out) {
    __shared__ __align__(16) ushort_t As0[128*64];
    __shared__ __align__(16) ushort_t Bs0[128*64];
    __shared__ __align__(16) ushort_t As1[128*64];
    __shared__ __align__(16) ushort_t Bs1[128*64];
    const int L = blockIdx.x + blockIdx.y * 65;
    const int xcd = L & 7, idx = L >> 3;
    const int wg = (xcd < 6 ? xcd * 49 : 6 * 49 + (xcd - 6) * 48) + idx;
    const int m0 = (wg / 6) * 128, c0 = (wg % 6) * 128;
    const int t = threadIdx.x;
    const int w = t >> 6, lane = t & 63, lc = lane & 15, lq = lane >> 4;
    const int wm = (w >> 1) * 64, wn = (w & 1) * 64;
    const int srow8 = w * 32 + (lane >> 3);
    const int gsw8  = (((lane & 7) ^ (lane >> 3)) & 7) * 8;

    v4f acc[4][4];
#pragma unroll
    for (int mt = 0; mt < 4; mt++)
#pragma unroll
        for (int nt = 0; nt < 4; nt++) acc[mt][nt] = (v4f){0.f, 0.f, 0.f, 0.f};

    auto STAGE = [&](ushort_t* Ad, ushort_t* Bd, int k0) {
#pragma unroll
        for (int i = 0; i < 4; i++) {
            int row = srow8 + i * 8;
            int m = m0 + row; if (m > NTOK - 1) m = NTOK - 1;
            GLOAD16(ab + (size_t)m * C_ + k0 + gsw8,           &Ad[(w*32 + i*8) * 64]);
            GLOAD16(wb + (size_t)(c0 + row) * C_ + k0 + gsw8,  &Bd[(w*32 + i*8) * 64]);
        }
    };
    auto COMPUTE = [&](const ushort_t* A, const ushort_t* B) {
#pragma unroll
        for (int kk = 0; kk < 64; kk += 32) {
            s8bf af[4], bf[4];
#pragma unroll
            for (int mt = 0; mt < 4; mt++)
                af[mt] = *(const s8bf*)&A[(wm + mt*16 + lc) * 64 + ((((kk>>3) + lq) ^ (lc & 7)) * 8)];
#pragma unroll
            for (int nt = 0; nt < 4; nt++)
                bf[nt] = *(const s8bf*)&B[(wn + nt*16 + lc) * 64 + ((((kk>>3) + lq) ^ (lc & 7)) * 8)];
#pragma unroll
            for (int mt = 0; mt < 4; mt++)
#pragma unroll
                for (int nt = 0; nt < 4; nt++)
                    acc[mt][nt] = __builtin_amdgcn_mfma_f32_16x16x32_bf16(af[mt], bf[nt], acc[mt][nt], 0, 0, 0);
        }
    };

    STAGE(As0, Bs0, 0);
#pragma unroll
    for (int it = 0; it < 6; ++it) {
        const int k0 = it * 128;
        if (k0 + 64 < C_) {
            STAGE(As1, Bs1, k0 + 64);
            asm volatile("s_waitcnt vmcnt(8)" ::: "memory");
        } else {
            asm volatile("s_waitcnt vmcnt(0)" ::: "memory");
        }
        SBAR();
        COMPUTE(As0, Bs0);
        SBAR();
        if (k0 + 128 < C_) {
            STAGE(As0, Bs0, k0 + 128);
            asm volatile("s_waitcnt vmcnt(8)" ::: "memory");
        } else {
            asm volatile("s_waitcnt vmcnt(0)" ::: "memory");
        }
        SBAR();
        COMPUTE(As1, Bs1);
        if (it < 5) SBAR();
    }

    float pb[4];
#pragma unroll
    for (int nt = 0; nt < 4; nt++) pb[nt] = bias[c0 + wn + nt*16 + lc];
#pragma unroll
    for (int mt = 0; mt < 4; mt++) {
#pragma unroll
        for (int r = 0; r < 4; r++) {
            int m = m0 + wm + mt*16 + lq*4 + r;
            if (m >= NTOK) continue;
#pragma unroll
            for (int nt = 0; nt < 4; nt++) {
                int c = c0 + wn + nt*16 + lc;
                out[(size_t)m * C_ + c] = acc[mt][nt][r] + pb[nt];
            }
        }
    }
}

extern "C" void kernel_launch(void* const* d_in, const int* in_sizes, int n_in,
                              void* d_out, int out_size, void* d_ws, size_t ws_size,
                              hipStream_t stream) {
    const float* x      = (const float*)d_in[0];
    const float* qkv_w  = (const float*)d_in[1];
    const float* proj_w = (const float*)d_in[2];
    const float* proj_b = (const float*)d_in[3];
    const float* rpe_w  = (const float*)d_in[4];
    float* out = (float*)d_out;

    char* ws = (char*)d_ws;
    ushort_t* xb   = (ushort_t*)(ws + XB_OFF_B);
    ushort_t* wqkv = (ushort_t*)(ws + WQKV_OFF_B);
    ushort_t* wprj = (ushort_t*)(ws + WPROJ_OFF_B);
    ushort_t* qb   = (ushort_t*)(ws + QB_OFF_B);
    ushort_t* kb   = (ushort_t*)(ws + KB_OFF_B);
    ushort_t* aob  = (ushort_t*)(ws + AOB_OFF_B);
    ushort_t* vt   = (ushort_t*)(ws + VT_OFF_B);
    unsigned char* bucketT = (unsigned char*)(ws + BUCKET_OFF_B);

    const int ncast = (NTOK*C_ + 3*C_*C_ + C_*C_) / 8;
    bucket_kernel<<<dim3((N_*NPAD + 255)/256), 256, 0, stream>>>(bucketT);
    cast_kernel<<<dim3((ncast + 255)/256), 256, 0, stream>>>(x, qkv_w, proj_w, xb, wqkv, wprj);
    qkv_kernel<<<dim3(65, 18), 256, 0, stream>>>(xb, wqkv, qb, kb, vt);
    attn_kernel<<<dim3(96, 17), 256, 0, stream>>>(qb, kb, vt, rpe_w, bucketT, aob);
    proj_kernel<<<dim3(65, 6), 256, 0, stream>>>(aob, wprj, proj_b, out);
}